// Round 7
// baseline (901.553 us; speedup 1.0000x reference)
//
#include <hip/hip_runtime.h>

// LightGCN: 3-layer propagation, 1.6M edges, D=128.
// R7: slice-major layer buffers [slice=8][node][8 uints(=32B)] with slice
// pinned to XCD via blockIdx&7. Each XCD's random gather working set becomes
// its own 3.2MB slice -> L2-resident (R6: 181MB FETCH = full 25.6MB x8 XCD
// replication via L3). Meta packed to 4B/edge (src 17b | bf16val 15b),
// nontemporal-loaded. CSR build = R6's proven LDS-staged two-phase.

static constexpr int USERS  = 50000;
static constexpr int NNODES = 100000;
static constexpr int DIM    = 128;
static constexpr int NEDGES = 1600000;
static constexpr long NELEM = (long)NNODES * DIM;     // 12.8M
static constexpr int NBK    = (NNODES + 255) / 256;   // 391 buckets x 256 nodes
static constexpr int EPW    = 8192;                   // edges per partition WG
static constexpr int NWG    = (NEDGES + EPW - 1) / EPW; // 196
static constexpr int SSROW  = NBK + 1;                // 392
static constexpr int SLICE  = 8;                      // uints per slice (32B)
static constexpr long SOFF  = (long)NNODES * SLICE;   // uints per slice region

__device__ __forceinline__ unsigned short f2bf(float f) {
    unsigned int u = __float_as_uint(f);
    unsigned int r = (u + 0x7FFFu + ((u >> 16) & 1)) >> 16;
    return (unsigned short)r;
}
__device__ __forceinline__ unsigned int pack2(float a, float b) {
    return (unsigned int)f2bf(a) | ((unsigned int)f2bf(b) << 16);
}
__device__ __forceinline__ float bflo(unsigned int p) { return __uint_as_float(p << 16); }
__device__ __forceinline__ float bfhi(unsigned int p) { return __uint_as_float(p & 0xFFFF0000u); }

// concat u/i embeds -> E0 slice-major bf16
__global__ void init_k(const float* __restrict__ uE, const float* __restrict__ iE,
                       unsigned int* __restrict__ E0) {
    long base = ((long)blockIdx.x * blockDim.x + threadIdx.x) * 8;
    if (base >= NELEM) return;
    const long usplit = (long)USERS * DIM;
    const float* s = (base < usplit) ? (uE + base) : (iE + (base - usplit));
    float4 f0 = *(const float4*)(s);
    float4 f1 = *(const float4*)(s + 4);
    uint4 o;
    o.x = pack2(f0.x, f0.y); o.y = pack2(f0.z, f0.w);
    o.z = pack2(f1.x, f1.y); o.w = pack2(f1.z, f1.w);
    int node = (int)(base >> 7);
    int d0 = (int)(base & 127);
    int c = d0 >> 4;
    int k0 = (d0 & 15) >> 1;                       // 0 or 4
    *(uint4*)(E0 + (long)c * SOFF + (long)node * SLICE + k0) = o;
}

// ---------- CSR build (R6 proven): LDS-staged partition ----------
__global__ void part_k(const int* __restrict__ esrc, const int* __restrict__ edst,
                       const float* __restrict__ eval,
                       int* __restrict__ ssP, int2* __restrict__ tmp) {
    __shared__ int2 stage[EPW];            // 64 KB
    __shared__ int hist[NBK];
    __shared__ int cursor[NBK];
    __shared__ int sp[256];
    int w = blockIdx.x, t = threadIdx.x;
    int ebase = w * EPW;
    int n = NEDGES - ebase; if (n > EPW) n = EPW;

    for (int b = t; b < NBK; b += 256) hist[b] = 0;
    __syncthreads();
    #pragma unroll
    for (int k = 0; k < EPW / 256; ++k) {
        int idx = k * 256 + t;
        if (idx < n) atomicAdd(&hist[edst[ebase + idx] >> 8], 1);
    }
    __syncthreads();
    int b0 = 2 * t, b1 = 2 * t + 1;
    int v0 = (b0 < NBK) ? hist[b0] : 0;
    int v1 = (b1 < NBK) ? hist[b1] : 0;
    int psum = v0 + v1;
    sp[t] = psum;
    __syncthreads();
    for (int o = 1; o < 256; o <<= 1) {
        int x = (t >= o) ? sp[t - o] : 0;
        __syncthreads();
        sp[t] += x;
        __syncthreads();
    }
    int pref = sp[t] - psum;
    if (b0 < NBK) cursor[b0] = pref;
    if (b1 < NBK) cursor[b1] = pref + v0;
    __syncthreads();
    for (int b = t; b < NBK; b += 256) ssP[w * SSROW + b] = cursor[b];
    if (t == 0) ssP[w * SSROW + NBK] = n;
    __syncthreads();
    #pragma unroll
    for (int k = 0; k < EPW / 256; ++k) {
        int idx = k * 256 + t;
        if (idx < n) {
            int e = ebase + idx;
            int d = edst[e];
            int p = atomicAdd(&cursor[d >> 8], 1);
            stage[p] = make_int2(esrc[e] | ((d & 255) << 17), __float_as_int(eval[e]));
        }
    }
    __syncthreads();
    #pragma unroll
    for (int k = 0; k < EPW / 256; ++k) {
        int idx = k * 256 + t;
        if (idx < n) tmp[ebase + idx] = stage[idx];
    }
}

__global__ void scanT_k(const int* __restrict__ ssP, int* __restrict__ bstart,
                        int* __restrict__ rs) {
    __shared__ int sp[1024];
    int t = threadIdx.x;
    int tot = 0;
    if (t < NBK) {
        for (int w = 0; w < NWG; ++w)
            tot += ssP[w * SSROW + t + 1] - ssP[w * SSROW + t];
    }
    sp[t] = tot;
    __syncthreads();
    for (int o = 1; o < 1024; o <<= 1) {
        int x = (t >= o) ? sp[t - o] : 0;
        __syncthreads();
        sp[t] += x;
        __syncthreads();
    }
    if (t < NBK) bstart[t] = sp[t] - tot;
    if (t == 0) { bstart[NBK] = NEDGES; rs[NNODES] = NEDGES; }
}

// per-bucket finalize -> rs[] + packed 4B meta: src(17) | bf16val[14:0] << 17
__global__ void fill2_k(const int2* __restrict__ tmp, const int* __restrict__ ssP,
                        const int* __restrict__ bstart,
                        int* __restrict__ rs, unsigned int* __restrict__ meta) {
    __shared__ int cnt[256];
    __shared__ int cur[256];
    __shared__ int sp2[256];
    int b = blockIdx.x, t = threadIdx.x;
    int base = bstart[b];
    int v = t >> 6, lane = t & 63;
    cnt[t] = 0;
    __syncthreads();
    for (int w = v; w < NWG; w += 4) {
        int s = ssP[w * SSROW + b];
        int e = ssP[w * SSROW + b + 1];
        const int2* seg = tmp + (long)w * EPW + s;
        for (int i = lane; i < e - s; i += 64)
            atomicAdd(&cnt[(seg[i].x >> 17) & 255], 1);
    }
    __syncthreads();
    int myc = cnt[t];
    sp2[t] = myc;
    __syncthreads();
    for (int o = 1; o < 256; o <<= 1) {
        int x = (t >= o) ? sp2[t - o] : 0;
        __syncthreads();
        sp2[t] += x;
        __syncthreads();
    }
    int start = base + sp2[t] - myc;
    int node = b * 256 + t;
    if (node < NNODES) rs[node] = start;
    cur[t] = start;
    __syncthreads();
    for (int w = v; w < NWG; w += 4) {
        int s = ssP[w * SSROW + b];
        int e = ssP[w * SSROW + b + 1];
        const int2* seg = tmp + (long)w * EPW + s;
        for (int i = lane; i < e - s; i += 64) {
            int2 m = seg[i];
            int slot = atomicAdd(&cur[(m.x >> 17) & 255], 1);
            unsigned int bv = (unsigned int)(f2bf(__int_as_float(m.y)) & 0x7FFF);
            meta[slot] = (unsigned int)(m.x & 0x1FFFF) | (bv << 17);
        }
    }
}

// ---------- gather: slice-pinned. c=blockIdx&7 -> XCD c reads only its 3.2MB
// slice (L2-resident). Wave = 8 edge-groups x 8 lanes; shfl-reduce over groups.
__global__ void gather_k(const int* __restrict__ rs, const unsigned int* __restrict__ meta,
                         const unsigned int* __restrict__ cur,
                         unsigned int* __restrict__ nxt) {
    int c = blockIdx.x & 7;
    int row = (blockIdx.x >> 3) * 4 + (threadIdx.x >> 6);
    if (row >= NNODES) return;
    int lane = threadIdx.x & 63;
    int g = lane >> 3, k = lane & 7;
    const unsigned int* curS = cur + (long)c * SOFF;
    int beg = rs[row], end = rs[row + 1];
    float sx = 0.f, sy = 0.f;
    for (int e = beg + g; e < end; e += 8) {
        unsigned int m = __builtin_nontemporal_load(&meta[e]);
        int src = (int)(m & 0x1FFFF);
        float v = __uint_as_float((m >> 17) << 16);   // bf16, sign=0
        unsigned int x = curS[src * SLICE + k];
        sx += bflo(x) * v;
        sy += bfhi(x) * v;
    }
    sx += __shfl_xor(sx, 8);  sy += __shfl_xor(sy, 8);
    sx += __shfl_xor(sx, 16); sy += __shfl_xor(sy, 16);
    sx += __shfl_xor(sx, 32); sy += __shfl_xor(sy, 32);
    if (g == 0)
        nxt[(long)c * SOFF + (long)row * SLICE + k] = pack2(sx, sy);
}

// ---------- final: out = embeds(f32) + L1 + L2 + L3 (slice-major in) ----------
__global__ void final_k(const float* __restrict__ uE, const float* __restrict__ iE,
                        const unsigned int* __restrict__ L1,
                        const unsigned int* __restrict__ L2,
                        const unsigned int* __restrict__ L3,
                        float* __restrict__ out) {
    long base = ((long)blockIdx.x * blockDim.x + threadIdx.x) * 8;
    if (base >= NELEM) return;
    const long usplit = (long)USERS * DIM;
    const float* s = (base < usplit) ? (uE + base) : (iE + (base - usplit));
    float4 a = *(const float4*)(s);
    float4 b = *(const float4*)(s + 4);
    int node = (int)(base >> 7);
    int d0 = (int)(base & 127);
    long off = (long)(d0 >> 4) * SOFF + (long)node * SLICE + ((d0 & 15) >> 1);
    uint4 l1 = *(const uint4*)(L1 + off);
    uint4 l2 = *(const uint4*)(L2 + off);
    uint4 l3 = *(const uint4*)(L3 + off);
    a.x += bflo(l1.x) + bflo(l2.x) + bflo(l3.x);
    a.y += bfhi(l1.x) + bfhi(l2.x) + bfhi(l3.x);
    a.z += bflo(l1.y) + bflo(l2.y) + bflo(l3.y);
    a.w += bfhi(l1.y) + bfhi(l2.y) + bfhi(l3.y);
    b.x += bflo(l1.z) + bflo(l2.z) + bflo(l3.z);
    b.y += bfhi(l1.z) + bfhi(l2.z) + bfhi(l3.z);
    b.z += bflo(l1.w) + bflo(l2.w) + bflo(l3.w);
    b.w += bfhi(l1.w) + bfhi(l2.w) + bfhi(l3.w);
    *(float4*)(out + base)     = a;
    *(float4*)(out + base + 4) = b;
}

// ---------- fallback: R2 atomic path ----------
__global__ void init_f32_k(const float* __restrict__ uE, const float* __restrict__ iE,
                           float* __restrict__ acc, float* __restrict__ cur) {
    long base = ((long)blockIdx.x * blockDim.x + threadIdx.x) * 8;
    if (base >= NELEM) return;
    const long usplit = (long)USERS * DIM;
    const float* s = (base < usplit) ? (uE + base) : (iE + (base - usplit));
    float4 f0 = *(const float4*)(s);
    float4 f1 = *(const float4*)(s + 4);
    *(float4*)(acc + base)     = f0;
    *(float4*)(acc + base + 4) = f1;
    *(float4*)(cur + base)     = f0;
    *(float4*)(cur + base + 4) = f1;
}
__global__ void scatter_k(const int* __restrict__ esrc, const int* __restrict__ edst,
                          const float* __restrict__ eval,
                          const float* __restrict__ cur, float* __restrict__ nxt) {
    long g = (long)blockIdx.x * blockDim.x + threadIdx.x;
    if (g >= (long)NEDGES * 32) return;
    int e  = (int)(g >> 5);
    int d0 = ((int)g & 31) * 4;
    float v = eval[e];
    float4 x = *(const float4*)(cur + (long)esrc[e] * DIM + d0);
    float* o = nxt + (long)edst[e] * DIM + d0;
    unsafeAtomicAdd(o + 0, x.x * v);
    unsafeAtomicAdd(o + 1, x.y * v);
    unsafeAtomicAdd(o + 2, x.z * v);
    unsafeAtomicAdd(o + 3, x.w * v);
}
__global__ void add_k(float* __restrict__ acc, const float* __restrict__ nxt) {
    long g = ((long)blockIdx.x * blockDim.x + threadIdx.x) * 4;
    if (g >= NELEM) return;
    float4 a = *(const float4*)(acc + g);
    float4 n = *(const float4*)(nxt + g);
    a.x += n.x; a.y += n.y; a.z += n.z; a.w += n.w;
    *(float4*)(acc + g) = a;
}

extern "C" void kernel_launch(void* const* d_in, const int* in_sizes, int n_in,
                              void* d_out, int out_size, void* d_ws, size_t ws_size,
                              hipStream_t stream) {
    const float* uE   = (const float*)d_in[0];
    const float* iE   = (const float*)d_in[1];
    const int*   esrc = (const int*)d_in[2];
    const int*   edst = (const int*)d_in[3];
    const float* eval = (const float*)d_in[4];
    float* out = (float*)d_out;

    char* ws = (char*)d_ws;
    const long NU = NELEM / 2;                      // uints per layer buffer
    unsigned int* E0 = (unsigned int*)ws;           // 25.6 MB
    unsigned int* L1 = E0 + NU;                     // 25.6 MB
    unsigned int* L2 = L1 + NU;                     // 25.6 MB
    unsigned int* L3 = L2 + NU;                     // 25.6 MB
    unsigned int* meta = (unsigned int*)(L3 + NU);  // 6.4 MB (packed)
    int*  rs     = (int*)(meta + NEDGES);           // NNODES+1
    int*  bstart = rs + NNODES + 1;                 // NBK+1
    size_t need  = (size_t)((char*)(bstart + NBK + 1) - ws);
    // aliases (dead before their host buffer is written):
    int2* tmp = (int2*)L2;                          // consumed by fill2 (pre-gather2)
    int*  ssP = (int*)L3;                           // consumed by fill2 (pre-gather3)

    if (ws_size >= need) {
        init_k<<<(int)((NELEM / 8 + 255) / 256), 256, 0, stream>>>(uE, iE, E0);

        part_k<<<NWG, 256, 0, stream>>>(esrc, edst, eval, ssP, tmp);
        scanT_k<<<1, 1024, 0, stream>>>(ssP, bstart, rs);
        fill2_k<<<NBK, 256, 0, stream>>>(tmp, ssP, bstart, rs, meta);

        const int gblocks = ((NNODES + 3) / 4) * 8;
        gather_k<<<gblocks, 256, 0, stream>>>(rs, meta, E0, L1);
        gather_k<<<gblocks, 256, 0, stream>>>(rs, meta, L1, L2);
        gather_k<<<gblocks, 256, 0, stream>>>(rs, meta, L2, L3);

        final_k<<<(int)((NELEM / 8 + 255) / 256), 256, 0, stream>>>(uE, iE, L1, L2, L3, out);
    } else {
        float* bufA = (float*)ws;
        float* bufB = bufA + NELEM;
        const size_t SZ = (size_t)NELEM * sizeof(float);
        init_f32_k<<<(int)((NELEM / 8 + 255) / 256), 256, 0, stream>>>(uE, iE, out, bufA);
        float* cur = bufA;
        float* nxt = bufB;
        for (int l = 0; l < 3; ++l) {
            hipMemsetAsync(nxt, 0, SZ, stream);
            long nthreads = (long)NEDGES * 32;
            scatter_k<<<(int)((nthreads + 255) / 256), 256, 0, stream>>>(esrc, edst, eval, cur, nxt);
            add_k<<<(int)((NELEM / 4 + 255) / 256), 256, 0, stream>>>(out, nxt);
            float* t = cur; cur = nxt; nxt = t;
        }
    }
}

// Round 8
// 375.606 us; speedup vs baseline: 2.4003x; 2.4003x over previous
//
#include <hip/hip_runtime.h>

// LightGCN: 3-layer propagation, 1.6M edges, D=128.
// R8: R6 row-major gather (64 lanes/row, bf16) + 4-wide MLP unroll (R3/R6/R7
// all sustained ~0.1 miss-lines/cyc/CU -> concurrency-bound, not bytes-bound),
// packed 4B meta (src 17b | bf16val 15b), layer-3 gather fused with the final
// out = emb + L1 + L2 + L3 epilogue (removes 179MB pass + L3 buffer).
// CSR build: R6/R7-proven LDS-staged two-phase (zero global atomics).

static constexpr int USERS  = 50000;
static constexpr int NNODES = 100000;
static constexpr int DIM    = 128;
static constexpr int NEDGES = 1600000;
static constexpr long NELEM = (long)NNODES * DIM;     // 12.8M
static constexpr int NBK    = (NNODES + 255) / 256;   // 391 buckets x 256 nodes
static constexpr int EPW    = 8192;                   // edges per partition WG
static constexpr int NWG    = (NEDGES + EPW - 1) / EPW; // 196
static constexpr int SSROW  = NBK + 1;                // 392

__device__ __forceinline__ unsigned short f2bf(float f) {
    unsigned int u = __float_as_uint(f);
    unsigned int r = (u + 0x7FFFu + ((u >> 16) & 1)) >> 16;
    return (unsigned short)r;
}
__device__ __forceinline__ unsigned int pack2(float a, float b) {
    return (unsigned int)f2bf(a) | ((unsigned int)f2bf(b) << 16);
}
__device__ __forceinline__ float bflo(unsigned int p) { return __uint_as_float(p << 16); }
__device__ __forceinline__ float bfhi(unsigned int p) { return __uint_as_float(p & 0xFFFF0000u); }

// concat u/i embeds -> E0 (bf16 as uint pairs, node-major)
__global__ void init_k(const float* __restrict__ uE, const float* __restrict__ iE,
                       unsigned int* __restrict__ E0) {
    long base = ((long)blockIdx.x * blockDim.x + threadIdx.x) * 8;
    if (base >= NELEM) return;
    const long usplit = (long)USERS * DIM;
    const float* s = (base < usplit) ? (uE + base) : (iE + (base - usplit));
    float4 f0 = *(const float4*)(s);
    float4 f1 = *(const float4*)(s + 4);
    uint4 o;
    o.x = pack2(f0.x, f0.y); o.y = pack2(f0.z, f0.w);
    o.z = pack2(f1.x, f1.y); o.w = pack2(f1.z, f1.w);
    *(uint4*)(E0 + base / 2) = o;
}

// ---------- CSR build (R6 proven): LDS-staged partition ----------
__global__ void part_k(const int* __restrict__ esrc, const int* __restrict__ edst,
                       const float* __restrict__ eval,
                       int* __restrict__ ssP, int2* __restrict__ tmp) {
    __shared__ int2 stage[EPW];            // 64 KB
    __shared__ int hist[NBK];
    __shared__ int cursor[NBK];
    __shared__ int sp[256];
    int w = blockIdx.x, t = threadIdx.x;
    int ebase = w * EPW;
    int n = NEDGES - ebase; if (n > EPW) n = EPW;

    for (int b = t; b < NBK; b += 256) hist[b] = 0;
    __syncthreads();
    #pragma unroll
    for (int k = 0; k < EPW / 256; ++k) {
        int idx = k * 256 + t;
        if (idx < n) atomicAdd(&hist[edst[ebase + idx] >> 8], 1);
    }
    __syncthreads();
    int b0 = 2 * t, b1 = 2 * t + 1;
    int v0 = (b0 < NBK) ? hist[b0] : 0;
    int v1 = (b1 < NBK) ? hist[b1] : 0;
    int psum = v0 + v1;
    sp[t] = psum;
    __syncthreads();
    for (int o = 1; o < 256; o <<= 1) {
        int x = (t >= o) ? sp[t - o] : 0;
        __syncthreads();
        sp[t] += x;
        __syncthreads();
    }
    int pref = sp[t] - psum;
    if (b0 < NBK) cursor[b0] = pref;
    if (b1 < NBK) cursor[b1] = pref + v0;
    __syncthreads();
    for (int b = t; b < NBK; b += 256) ssP[w * SSROW + b] = cursor[b];
    if (t == 0) ssP[w * SSROW + NBK] = n;
    __syncthreads();
    #pragma unroll
    for (int k = 0; k < EPW / 256; ++k) {
        int idx = k * 256 + t;
        if (idx < n) {
            int e = ebase + idx;
            int d = edst[e];
            int p = atomicAdd(&cursor[d >> 8], 1);
            stage[p] = make_int2(esrc[e] | ((d & 255) << 17), __float_as_int(eval[e]));
        }
    }
    __syncthreads();
    #pragma unroll
    for (int k = 0; k < EPW / 256; ++k) {
        int idx = k * 256 + t;
        if (idx < n) tmp[ebase + idx] = stage[idx];
    }
}

__global__ void scanT_k(const int* __restrict__ ssP, int* __restrict__ bstart,
                        int* __restrict__ rs) {
    __shared__ int sp[1024];
    int t = threadIdx.x;
    int tot = 0;
    if (t < NBK) {
        for (int w = 0; w < NWG; ++w)
            tot += ssP[w * SSROW + t + 1] - ssP[w * SSROW + t];
    }
    sp[t] = tot;
    __syncthreads();
    for (int o = 1; o < 1024; o <<= 1) {
        int x = (t >= o) ? sp[t - o] : 0;
        __syncthreads();
        sp[t] += x;
        __syncthreads();
    }
    if (t < NBK) bstart[t] = sp[t] - tot;
    if (t == 0) { bstart[NBK] = NEDGES; rs[NNODES] = NEDGES; }
}

// per-bucket finalize -> rs[] + packed 4B meta: src(17) | bf16val[14:0] << 17
__global__ void fill2_k(const int2* __restrict__ tmp, const int* __restrict__ ssP,
                        const int* __restrict__ bstart,
                        int* __restrict__ rs, unsigned int* __restrict__ meta) {
    __shared__ int cnt[256];
    __shared__ int cur[256];
    __shared__ int sp2[256];
    int b = blockIdx.x, t = threadIdx.x;
    int base = bstart[b];
    int v = t >> 6, lane = t & 63;
    cnt[t] = 0;
    __syncthreads();
    for (int w = v; w < NWG; w += 4) {
        int s = ssP[w * SSROW + b];
        int e = ssP[w * SSROW + b + 1];
        const int2* seg = tmp + (long)w * EPW + s;
        for (int i = lane; i < e - s; i += 64)
            atomicAdd(&cnt[(seg[i].x >> 17) & 255], 1);
    }
    __syncthreads();
    int myc = cnt[t];
    sp2[t] = myc;
    __syncthreads();
    for (int o = 1; o < 256; o <<= 1) {
        int x = (t >= o) ? sp2[t - o] : 0;
        __syncthreads();
        sp2[t] += x;
        __syncthreads();
    }
    int start = base + sp2[t] - myc;
    int node = b * 256 + t;
    if (node < NNODES) rs[node] = start;
    cur[t] = start;
    __syncthreads();
    for (int w = v; w < NWG; w += 4) {
        int s = ssP[w * SSROW + b];
        int e = ssP[w * SSROW + b + 1];
        const int2* seg = tmp + (long)w * EPW + s;
        for (int i = lane; i < e - s; i += 64) {
            int2 m = seg[i];
            int slot = atomicAdd(&cur[(m.x >> 17) & 255], 1);
            unsigned int bv = (unsigned int)(f2bf(__int_as_float(m.y)) & 0x7FFF);
            meta[slot] = (unsigned int)(m.x & 0x1FFFF) | (bv << 17);
        }
    }
}

// ---------- gather (layers 1,2): 1 wave/row, 4-wide unrolled MLP ----------
__global__ void gather_k(const int* __restrict__ rs, const unsigned int* __restrict__ meta,
                         const unsigned int* __restrict__ cur,
                         unsigned int* __restrict__ nxt) {
    int row = blockIdx.x * 4 + (threadIdx.x >> 6);
    if (row >= NNODES) return;
    int lane = threadIdx.x & 63;
    int beg = rs[row], end = rs[row + 1];
    float ax = 0.f, ay = 0.f, bx = 0.f, by = 0.f;
    float cx = 0.f, cy = 0.f, dx = 0.f, dy = 0.f;
    int i = beg;
    for (; i + 4 <= end; i += 4) {                    // 4 independent chains
        unsigned int m0 = __builtin_nontemporal_load(&meta[i]);
        unsigned int m1 = __builtin_nontemporal_load(&meta[i + 1]);
        unsigned int m2 = __builtin_nontemporal_load(&meta[i + 2]);
        unsigned int m3 = __builtin_nontemporal_load(&meta[i + 3]);
        unsigned int p0 = cur[((m0 & 0x1FFFF) << 6) + lane];
        unsigned int p1 = cur[((m1 & 0x1FFFF) << 6) + lane];
        unsigned int p2 = cur[((m2 & 0x1FFFF) << 6) + lane];
        unsigned int p3 = cur[((m3 & 0x1FFFF) << 6) + lane];
        float v0 = __uint_as_float((m0 >> 17) << 16);
        float v1 = __uint_as_float((m1 >> 17) << 16);
        float v2 = __uint_as_float((m2 >> 17) << 16);
        float v3 = __uint_as_float((m3 >> 17) << 16);
        ax += bflo(p0) * v0;  ay += bfhi(p0) * v0;
        bx += bflo(p1) * v1;  by += bfhi(p1) * v1;
        cx += bflo(p2) * v2;  cy += bfhi(p2) * v2;
        dx += bflo(p3) * v3;  dy += bfhi(p3) * v3;
    }
    for (; i < end; ++i) {
        unsigned int m = __builtin_nontemporal_load(&meta[i]);
        unsigned int p = cur[((m & 0x1FFFF) << 6) + lane];
        float v = __uint_as_float((m >> 17) << 16);
        ax += bflo(p) * v;  ay += bfhi(p) * v;
    }
    nxt[(row << 6) + lane] = pack2((ax + bx) + (cx + dx), (ay + by) + (cy + dy));
}

// ---------- layer 3 fused with final: out = emb + L1 + L2 + sum ----------
__global__ void gather_last_k(const int* __restrict__ rs, const unsigned int* __restrict__ meta,
                              const unsigned int* __restrict__ cur,   // = L2 buffer
                              const unsigned int* __restrict__ L1,
                              const float* __restrict__ uE, const float* __restrict__ iE,
                              float* __restrict__ out) {
    int row = blockIdx.x * 4 + (threadIdx.x >> 6);
    if (row >= NNODES) return;
    int lane = threadIdx.x & 63;
    int beg = rs[row], end = rs[row + 1];
    float ax = 0.f, ay = 0.f, bx = 0.f, by = 0.f;
    float cx = 0.f, cy = 0.f, dx = 0.f, dy = 0.f;
    int i = beg;
    for (; i + 4 <= end; i += 4) {
        unsigned int m0 = __builtin_nontemporal_load(&meta[i]);
        unsigned int m1 = __builtin_nontemporal_load(&meta[i + 1]);
        unsigned int m2 = __builtin_nontemporal_load(&meta[i + 2]);
        unsigned int m3 = __builtin_nontemporal_load(&meta[i + 3]);
        unsigned int p0 = cur[((m0 & 0x1FFFF) << 6) + lane];
        unsigned int p1 = cur[((m1 & 0x1FFFF) << 6) + lane];
        unsigned int p2 = cur[((m2 & 0x1FFFF) << 6) + lane];
        unsigned int p3 = cur[((m3 & 0x1FFFF) << 6) + lane];
        float v0 = __uint_as_float((m0 >> 17) << 16);
        float v1 = __uint_as_float((m1 >> 17) << 16);
        float v2 = __uint_as_float((m2 >> 17) << 16);
        float v3 = __uint_as_float((m3 >> 17) << 16);
        ax += bflo(p0) * v0;  ay += bfhi(p0) * v0;
        bx += bflo(p1) * v1;  by += bfhi(p1) * v1;
        cx += bflo(p2) * v2;  cy += bfhi(p2) * v2;
        dx += bflo(p3) * v3;  dy += bfhi(p3) * v3;
    }
    for (; i < end; ++i) {
        unsigned int m = __builtin_nontemporal_load(&meta[i]);
        unsigned int p = cur[((m & 0x1FFFF) << 6) + lane];
        float v = __uint_as_float((m >> 17) << 16);
        ax += bflo(p) * v;  ay += bfhi(p) * v;
    }
    float sx = (ax + bx) + (cx + dx);
    float sy = (ay + by) + (cy + dy);
    const float* emb = (row < USERS) ? (uE + (long)row * DIM)
                                     : (iE + (long)(row - USERS) * DIM);
    float2 e = *(const float2*)(emb + lane * 2);
    unsigned int l1 = L1[(row << 6) + lane];
    unsigned int l2 = cur[(row << 6) + lane];       // sequential row read
    float2 o;
    o.x = e.x + bflo(l1) + bflo(l2) + sx;
    o.y = e.y + bfhi(l1) + bfhi(l2) + sy;
    *(float2*)(out + (long)row * DIM + lane * 2) = o;
}

// ---------- fallback: R2 atomic path ----------
__global__ void init_f32_k(const float* __restrict__ uE, const float* __restrict__ iE,
                           float* __restrict__ acc, float* __restrict__ cur) {
    long base = ((long)blockIdx.x * blockDim.x + threadIdx.x) * 8;
    if (base >= NELEM) return;
    const long usplit = (long)USERS * DIM;
    const float* s = (base < usplit) ? (uE + base) : (iE + (base - usplit));
    float4 f0 = *(const float4*)(s);
    float4 f1 = *(const float4*)(s + 4);
    *(float4*)(acc + base)     = f0;
    *(float4*)(acc + base + 4) = f1;
    *(float4*)(cur + base)     = f0;
    *(float4*)(cur + base + 4) = f1;
}
__global__ void scatter_k(const int* __restrict__ esrc, const int* __restrict__ edst,
                          const float* __restrict__ eval,
                          const float* __restrict__ cur, float* __restrict__ nxt) {
    long g = (long)blockIdx.x * blockDim.x + threadIdx.x;
    if (g >= (long)NEDGES * 32) return;
    int e  = (int)(g >> 5);
    int d0 = ((int)g & 31) * 4;
    float v = eval[e];
    float4 x = *(const float4*)(cur + (long)esrc[e] * DIM + d0);
    float* o = nxt + (long)edst[e] * DIM + d0;
    unsafeAtomicAdd(o + 0, x.x * v);
    unsafeAtomicAdd(o + 1, x.y * v);
    unsafeAtomicAdd(o + 2, x.z * v);
    unsafeAtomicAdd(o + 3, x.w * v);
}
__global__ void add_k(float* __restrict__ acc, const float* __restrict__ nxt) {
    long g = ((long)blockIdx.x * blockDim.x + threadIdx.x) * 4;
    if (g >= NELEM) return;
    float4 a = *(const float4*)(acc + g);
    float4 n = *(const float4*)(nxt + g);
    a.x += n.x; a.y += n.y; a.z += n.z; a.w += n.w;
    *(float4*)(acc + g) = a;
}

extern "C" void kernel_launch(void* const* d_in, const int* in_sizes, int n_in,
                              void* d_out, int out_size, void* d_ws, size_t ws_size,
                              hipStream_t stream) {
    const float* uE   = (const float*)d_in[0];
    const float* iE   = (const float*)d_in[1];
    const int*   esrc = (const int*)d_in[2];
    const int*   edst = (const int*)d_in[3];
    const float* eval = (const float*)d_in[4];
    float* out = (float*)d_out;

    char* ws = (char*)d_ws;
    const long NU = NELEM / 2;                      // uints per layer buffer
    unsigned int* E0  = (unsigned int*)ws;          // 25.6 MB
    unsigned int* L1  = E0 + NU;                    // 25.6 MB
    unsigned int* L2b = L1 + NU;                    // 25.6 MB
    unsigned int* meta = (unsigned int*)(L2b + NU); // 6.4 MB (packed)
    int*  rs     = (int*)(meta + NEDGES);           // NNODES+1
    int*  bstart = rs + NNODES + 1;                 // NBK+1
    int*  ssP    = bstart + NBK + 1;                // NWG*SSROW (0.31 MB)
    size_t need  = (size_t)((char*)(ssP + NWG * SSROW) - ws);
    // tmp aliases L2b: written by part_k, consumed by fill2_k, both complete
    // before gather2 writes L2b.
    int2* tmp = (int2*)L2b;

    if (ws_size >= need) {
        init_k<<<(int)((NELEM / 8 + 255) / 256), 256, 0, stream>>>(uE, iE, E0);

        part_k<<<NWG, 256, 0, stream>>>(esrc, edst, eval, ssP, tmp);
        scanT_k<<<1, 1024, 0, stream>>>(ssP, bstart, rs);
        fill2_k<<<NBK, 256, 0, stream>>>(tmp, ssP, bstart, rs, meta);

        const int gblocks = (NNODES + 3) / 4;
        gather_k<<<gblocks, 256, 0, stream>>>(rs, meta, E0, L1);
        gather_k<<<gblocks, 256, 0, stream>>>(rs, meta, L1, L2b);
        gather_last_k<<<gblocks, 256, 0, stream>>>(rs, meta, L2b, L1, uE, iE, out);
    } else {
        float* bufA = (float*)ws;
        float* bufB = bufA + NELEM;
        const size_t SZ = (size_t)NELEM * sizeof(float);
        init_f32_k<<<(int)((NELEM / 8 + 255) / 256), 256, 0, stream>>>(uE, iE, out, bufA);
        float* cur = bufA;
        float* nxt = bufB;
        for (int l = 0; l < 3; ++l) {
            hipMemsetAsync(nxt, 0, SZ, stream);
            long nthreads = (long)NEDGES * 32;
            scatter_k<<<(int)((nthreads + 255) / 256), 256, 0, stream>>>(esrc, edst, eval, cur, nxt);
            add_k<<<(int)((NELEM / 4 + 255) / 256), 256, 0, stream>>>(out, nxt);
            float* t = cur; cur = nxt; nxt = t;
        }
    }
}

// Round 9
// 366.067 us; speedup vs baseline: 2.4628x; 1.0261x over previous
//
#include <hip/hip_runtime.h>

// LightGCN: 3-layer propagation, 1.6M edges, D=128.
// R9: overhead pass. Gathers are at (compulsory per-XCD miss bytes 181MB) x
// (~2.6 TB/s L2-miss-path ceiling) -- R8 analysis: FETCH == distinct-rows
// floor, L2 captures all intra-XCD reuse. So: (1) init merged into part_k
// (grid-split) so init blocks fill CUs idle during the 196-block LDS-heavy
// partition; (2) scanT kernel removed (global bucket counts via atomics,
// redundant per-block LDS scan in fill2); (3) gather_last uses bf16 E0 for
// the embed term (-25.6MB f32 stream).

static constexpr int USERS  = 50000;
static constexpr int NNODES = 100000;
static constexpr int DIM    = 128;
static constexpr int NEDGES = 1600000;
static constexpr long NELEM = (long)NNODES * DIM;     // 12.8M
static constexpr int NBK    = (NNODES + 255) / 256;   // 391 buckets x 256 nodes
static constexpr int EPW    = 8192;                   // edges per partition WG
static constexpr int NWG    = (NEDGES + EPW - 1) / EPW; // 196
static constexpr int SSROW  = NBK + 1;                // 392
static constexpr int INITB  = (int)((NELEM / 16 + 255) / 256); // 3125

__device__ __forceinline__ unsigned short f2bf(float f) {
    unsigned int u = __float_as_uint(f);
    unsigned int r = (u + 0x7FFFu + ((u >> 16) & 1)) >> 16;
    return (unsigned short)r;
}
__device__ __forceinline__ unsigned int pack2(float a, float b) {
    return (unsigned int)f2bf(a) | ((unsigned int)f2bf(b) << 16);
}
__device__ __forceinline__ float bflo(unsigned int p) { return __uint_as_float(p << 16); }
__device__ __forceinline__ float bfhi(unsigned int p) { return __uint_as_float(p & 0xFFFF0000u); }

// ---------- fused: blocks [0,NWG) partition edges; rest convert embeds ----------
__global__ void __launch_bounds__(256) initpart_k(
    const float* __restrict__ uE, const float* __restrict__ iE,
    const int* __restrict__ esrc, const int* __restrict__ edst,
    const float* __restrict__ eval,
    unsigned int* __restrict__ E0, int* __restrict__ ssP,
    int* __restrict__ gcnt, int2* __restrict__ tmp) {
    __shared__ int2 stage[EPW];            // 64 KB
    __shared__ int hist[NBK];
    __shared__ int cursor[NBK];
    __shared__ int sp[256];
    int t = threadIdx.x;

    if (blockIdx.x >= NWG) {
        // ---- init portion: 16 elems/thread ----
        long base = ((long)(blockIdx.x - NWG) * 256 + t) * 16;
        if (base >= NELEM) return;
        const long usplit = (long)USERS * DIM;     // 6.4M, divisible by 16
        const float* s = (base < usplit) ? (uE + base) : (iE + (base - usplit));
        #pragma unroll
        for (int h = 0; h < 2; ++h) {
            float4 f0 = *(const float4*)(s + h * 8);
            float4 f1 = *(const float4*)(s + h * 8 + 4);
            uint4 o;
            o.x = pack2(f0.x, f0.y); o.y = pack2(f0.z, f0.w);
            o.z = pack2(f1.x, f1.y); o.w = pack2(f1.z, f1.w);
            *(uint4*)(E0 + base / 2 + h * 4) = o;
        }
        return;
    }

    // ---- partition portion (R6-proven) ----
    int w = blockIdx.x;
    int ebase = w * EPW;
    int n = NEDGES - ebase; if (n > EPW) n = EPW;

    for (int b = t; b < NBK; b += 256) hist[b] = 0;
    __syncthreads();
    #pragma unroll
    for (int k = 0; k < EPW / 256; ++k) {
        int idx = k * 256 + t;
        if (idx < n) atomicAdd(&hist[edst[ebase + idx] >> 8], 1);
    }
    __syncthreads();
    // export bucket totals to global counts (replaces scanT's reduction)
    for (int b = t; b < NBK; b += 256)
        if (hist[b]) atomicAdd(&gcnt[b], hist[b]);
    // exclusive scan hist -> cursor
    int b0 = 2 * t, b1 = 2 * t + 1;
    int v0 = (b0 < NBK) ? hist[b0] : 0;
    int v1 = (b1 < NBK) ? hist[b1] : 0;
    int psum = v0 + v1;
    sp[t] = psum;
    __syncthreads();
    for (int o = 1; o < 256; o <<= 1) {
        int x = (t >= o) ? sp[t - o] : 0;
        __syncthreads();
        sp[t] += x;
        __syncthreads();
    }
    int pref = sp[t] - psum;
    if (b0 < NBK) cursor[b0] = pref;
    if (b1 < NBK) cursor[b1] = pref + v0;
    __syncthreads();
    for (int b = t; b < NBK; b += 256) ssP[w * SSROW + b] = cursor[b];
    if (t == 0) ssP[w * SSROW + NBK] = n;
    __syncthreads();
    #pragma unroll
    for (int k = 0; k < EPW / 256; ++k) {
        int idx = k * 256 + t;
        if (idx < n) {
            int e = ebase + idx;
            int d = edst[e];
            int p = atomicAdd(&cursor[d >> 8], 1);
            stage[p] = make_int2(esrc[e] | ((d & 255) << 17), __float_as_int(eval[e]));
        }
    }
    __syncthreads();
    #pragma unroll
    for (int k = 0; k < EPW / 256; ++k) {
        int idx = k * 256 + t;
        if (idx < n) tmp[ebase + idx] = stage[idx];
    }
}

// per-bucket finalize: inline bucket-base scan, LDS node count+scan -> rs,
// dense meta (packed 4B: src 17b | bf16val 15b)
__global__ void fill2_k(const int2* __restrict__ tmp, const int* __restrict__ ssP,
                        const int* __restrict__ gcnt,
                        int* __restrict__ rs, unsigned int* __restrict__ meta) {
    __shared__ int cnt[256];
    __shared__ int cur[256];
    __shared__ int sp2[256];
    __shared__ int sbase;
    int b = blockIdx.x, t = threadIdx.x;
    // exclusive-scan gcnt (391) redundantly; keep only prefix at b
    int b0 = 2 * t, b1 = 2 * t + 1;
    int g0 = (b0 < NBK) ? gcnt[b0] : 0;
    int g1 = (b1 < NBK) ? gcnt[b1] : 0;
    int ps = g0 + g1;
    sp2[t] = ps;
    __syncthreads();
    for (int o = 1; o < 256; o <<= 1) {
        int x = (t >= o) ? sp2[t - o] : 0;
        __syncthreads();
        sp2[t] += x;
        __syncthreads();
    }
    int pref = sp2[t] - ps;
    if (b0 == b) sbase = pref;
    if (b1 == b) sbase = pref + g0;
    if (b == 0 && t == 0) rs[NNODES] = NEDGES;
    cnt[t] = 0;
    __syncthreads();
    int base = sbase;
    int v = t >> 6, lane = t & 63;
    for (int w = v; w < NWG; w += 4) {
        int s = ssP[w * SSROW + b];
        int e = ssP[w * SSROW + b + 1];
        const int2* seg = tmp + (long)w * EPW + s;
        for (int i = lane; i < e - s; i += 64)
            atomicAdd(&cnt[(seg[i].x >> 17) & 255], 1);
    }
    __syncthreads();
    int myc = cnt[t];
    sp2[t] = myc;
    __syncthreads();
    for (int o = 1; o < 256; o <<= 1) {
        int x = (t >= o) ? sp2[t - o] : 0;
        __syncthreads();
        sp2[t] += x;
        __syncthreads();
    }
    int start = base + sp2[t] - myc;
    int node = b * 256 + t;
    if (node < NNODES) rs[node] = start;
    cur[t] = start;
    __syncthreads();
    for (int w = v; w < NWG; w += 4) {
        int s = ssP[w * SSROW + b];
        int e = ssP[w * SSROW + b + 1];
        const int2* seg = tmp + (long)w * EPW + s;
        for (int i = lane; i < e - s; i += 64) {
            int2 m = seg[i];
            int slot = atomicAdd(&cur[(m.x >> 17) & 255], 1);
            unsigned int bv = (unsigned int)(f2bf(__int_as_float(m.y)) & 0x7FFF);
            meta[slot] = (unsigned int)(m.x & 0x1FFFF) | (bv << 17);
        }
    }
}

// ---------- gather (layers 1,2): 1 wave/row, 4-wide unrolled MLP ----------
__global__ void gather_k(const int* __restrict__ rs, const unsigned int* __restrict__ meta,
                         const unsigned int* __restrict__ cur,
                         unsigned int* __restrict__ nxt) {
    int row = blockIdx.x * 4 + (threadIdx.x >> 6);
    if (row >= NNODES) return;
    int lane = threadIdx.x & 63;
    int beg = rs[row], end = rs[row + 1];
    float ax = 0.f, ay = 0.f, bx = 0.f, by = 0.f;
    float cx = 0.f, cy = 0.f, dx = 0.f, dy = 0.f;
    int i = beg;
    for (; i + 4 <= end; i += 4) {
        unsigned int m0 = __builtin_nontemporal_load(&meta[i]);
        unsigned int m1 = __builtin_nontemporal_load(&meta[i + 1]);
        unsigned int m2 = __builtin_nontemporal_load(&meta[i + 2]);
        unsigned int m3 = __builtin_nontemporal_load(&meta[i + 3]);
        unsigned int p0 = cur[((m0 & 0x1FFFF) << 6) + lane];
        unsigned int p1 = cur[((m1 & 0x1FFFF) << 6) + lane];
        unsigned int p2 = cur[((m2 & 0x1FFFF) << 6) + lane];
        unsigned int p3 = cur[((m3 & 0x1FFFF) << 6) + lane];
        float v0 = __uint_as_float((m0 >> 17) << 16);
        float v1 = __uint_as_float((m1 >> 17) << 16);
        float v2 = __uint_as_float((m2 >> 17) << 16);
        float v3 = __uint_as_float((m3 >> 17) << 16);
        ax += bflo(p0) * v0;  ay += bfhi(p0) * v0;
        bx += bflo(p1) * v1;  by += bfhi(p1) * v1;
        cx += bflo(p2) * v2;  cy += bfhi(p2) * v2;
        dx += bflo(p3) * v3;  dy += bfhi(p3) * v3;
    }
    for (; i < end; ++i) {
        unsigned int m = __builtin_nontemporal_load(&meta[i]);
        unsigned int p = cur[((m & 0x1FFFF) << 6) + lane];
        float v = __uint_as_float((m >> 17) << 16);
        ax += bflo(p) * v;  ay += bfhi(p) * v;
    }
    nxt[(row << 6) + lane] = pack2((ax + bx) + (cx + dx), (ay + by) + (cy + dy));
}

// ---------- layer 3 fused with final: out = E0 + L1 + L2 + sum ----------
__global__ void gather_last_k(const int* __restrict__ rs, const unsigned int* __restrict__ meta,
                              const unsigned int* __restrict__ cur,   // = L2 buffer
                              const unsigned int* __restrict__ L1,
                              const unsigned int* __restrict__ E0,
                              float* __restrict__ out) {
    int row = blockIdx.x * 4 + (threadIdx.x >> 6);
    if (row >= NNODES) return;
    int lane = threadIdx.x & 63;
    int beg = rs[row], end = rs[row + 1];
    float ax = 0.f, ay = 0.f, bx = 0.f, by = 0.f;
    float cx = 0.f, cy = 0.f, dx = 0.f, dy = 0.f;
    int i = beg;
    for (; i + 4 <= end; i += 4) {
        unsigned int m0 = __builtin_nontemporal_load(&meta[i]);
        unsigned int m1 = __builtin_nontemporal_load(&meta[i + 1]);
        unsigned int m2 = __builtin_nontemporal_load(&meta[i + 2]);
        unsigned int m3 = __builtin_nontemporal_load(&meta[i + 3]);
        unsigned int p0 = cur[((m0 & 0x1FFFF) << 6) + lane];
        unsigned int p1 = cur[((m1 & 0x1FFFF) << 6) + lane];
        unsigned int p2 = cur[((m2 & 0x1FFFF) << 6) + lane];
        unsigned int p3 = cur[((m3 & 0x1FFFF) << 6) + lane];
        float v0 = __uint_as_float((m0 >> 17) << 16);
        float v1 = __uint_as_float((m1 >> 17) << 16);
        float v2 = __uint_as_float((m2 >> 17) << 16);
        float v3 = __uint_as_float((m3 >> 17) << 16);
        ax += bflo(p0) * v0;  ay += bfhi(p0) * v0;
        bx += bflo(p1) * v1;  by += bfhi(p1) * v1;
        cx += bflo(p2) * v2;  cy += bfhi(p2) * v2;
        dx += bflo(p3) * v3;  dy += bfhi(p3) * v3;
    }
    for (; i < end; ++i) {
        unsigned int m = __builtin_nontemporal_load(&meta[i]);
        unsigned int p = cur[((m & 0x1FFFF) << 6) + lane];
        float v = __uint_as_float((m >> 17) << 16);
        ax += bflo(p) * v;  ay += bfhi(p) * v;
    }
    float sx = (ax + bx) + (cx + dx);
    float sy = (ay + by) + (cy + dy);
    unsigned int e0 = E0[(row << 6) + lane];
    unsigned int l1 = L1[(row << 6) + lane];
    unsigned int l2 = cur[(row << 6) + lane];
    float2 o;
    o.x = bflo(e0) + bflo(l1) + bflo(l2) + sx;
    o.y = bfhi(e0) + bfhi(l1) + bfhi(l2) + sy;
    *(float2*)(out + (long)row * DIM + lane * 2) = o;
}

// ---------- fallback: R2 atomic path ----------
__global__ void init_f32_k(const float* __restrict__ uE, const float* __restrict__ iE,
                           float* __restrict__ acc, float* __restrict__ cur) {
    long base = ((long)blockIdx.x * blockDim.x + threadIdx.x) * 8;
    if (base >= NELEM) return;
    const long usplit = (long)USERS * DIM;
    const float* s = (base < usplit) ? (uE + base) : (iE + (base - usplit));
    float4 f0 = *(const float4*)(s);
    float4 f1 = *(const float4*)(s + 4);
    *(float4*)(acc + base)     = f0;
    *(float4*)(acc + base + 4) = f1;
    *(float4*)(cur + base)     = f0;
    *(float4*)(cur + base + 4) = f1;
}
__global__ void scatter_k(const int* __restrict__ esrc, const int* __restrict__ edst,
                          const float* __restrict__ eval,
                          const float* __restrict__ cur, float* __restrict__ nxt) {
    long g = (long)blockIdx.x * blockDim.x + threadIdx.x;
    if (g >= (long)NEDGES * 32) return;
    int e  = (int)(g >> 5);
    int d0 = ((int)g & 31) * 4;
    float v = eval[e];
    float4 x = *(const float4*)(cur + (long)esrc[e] * DIM + d0);
    float* o = nxt + (long)edst[e] * DIM + d0;
    unsafeAtomicAdd(o + 0, x.x * v);
    unsafeAtomicAdd(o + 1, x.y * v);
    unsafeAtomicAdd(o + 2, x.z * v);
    unsafeAtomicAdd(o + 3, x.w * v);
}
__global__ void add_k(float* __restrict__ acc, const float* __restrict__ nxt) {
    long g = ((long)blockIdx.x * blockDim.x + threadIdx.x) * 4;
    if (g >= NELEM) return;
    float4 a = *(const float4*)(acc + g);
    float4 n = *(const float4*)(nxt + g);
    a.x += n.x; a.y += n.y; a.z += n.z; a.w += n.w;
    *(float4*)(acc + g) = a;
}

extern "C" void kernel_launch(void* const* d_in, const int* in_sizes, int n_in,
                              void* d_out, int out_size, void* d_ws, size_t ws_size,
                              hipStream_t stream) {
    const float* uE   = (const float*)d_in[0];
    const float* iE   = (const float*)d_in[1];
    const int*   esrc = (const int*)d_in[2];
    const int*   edst = (const int*)d_in[3];
    const float* eval = (const float*)d_in[4];
    float* out = (float*)d_out;

    char* ws = (char*)d_ws;
    const long NU = NELEM / 2;                      // uints per layer buffer
    unsigned int* E0  = (unsigned int*)ws;          // 25.6 MB
    unsigned int* L1  = E0 + NU;                    // 25.6 MB
    unsigned int* L2b = L1 + NU;                    // 25.6 MB
    unsigned int* meta = (unsigned int*)(L2b + NU); // 6.4 MB (packed)
    int*  rs     = (int*)(meta + NEDGES);           // NNODES+1
    int*  gcnt   = rs + NNODES + 1;                 // NBK
    int*  ssP    = gcnt + NBK;                      // NWG*SSROW (0.31 MB)
    size_t need  = (size_t)((char*)(ssP + NWG * SSROW) - ws);
    // tmp aliases L2b: written by part portion, consumed by fill2_k, both
    // complete before gather2 writes L2b.
    int2* tmp = (int2*)L2b;

    if (ws_size >= need) {
        hipMemsetAsync(gcnt, 0, (size_t)NBK * sizeof(int), stream);
        initpart_k<<<NWG + INITB, 256, 0, stream>>>(uE, iE, esrc, edst, eval,
                                                    E0, ssP, gcnt, tmp);
        fill2_k<<<NBK, 256, 0, stream>>>(tmp, ssP, gcnt, rs, meta);

        const int gblocks = (NNODES + 3) / 4;
        gather_k<<<gblocks, 256, 0, stream>>>(rs, meta, E0, L1);
        gather_k<<<gblocks, 256, 0, stream>>>(rs, meta, L1, L2b);
        gather_last_k<<<gblocks, 256, 0, stream>>>(rs, meta, L2b, L1, E0, out);
    } else {
        float* bufA = (float*)ws;
        float* bufB = bufA + NELEM;
        const size_t SZ = (size_t)NELEM * sizeof(float);
        init_f32_k<<<(int)((NELEM / 8 + 255) / 256), 256, 0, stream>>>(uE, iE, out, bufA);
        float* cur = bufA;
        float* nxt = bufB;
        for (int l = 0; l < 3; ++l) {
            hipMemsetAsync(nxt, 0, SZ, stream);
            long nthreads = (long)NEDGES * 32;
            scatter_k<<<(int)((nthreads + 255) / 256), 256, 0, stream>>>(esrc, edst, eval, cur, nxt);
            add_k<<<(int)((NELEM / 4 + 255) / 256), 256, 0, stream>>>(out, nxt);
            float* t = cur; cur = nxt; nxt = t;
        }
    }
}

// Round 10
// 295.885 us; speedup vs baseline: 3.0470x; 1.2372x over previous
//
#include <hip/hip_runtime.h>

// LightGCN: 3-layer propagation, 1.6M edges, D=128.
// R10: build-overhead pass. Gathers sit at compulsory-miss x ~2.6TB/s floor
// (R8/R9 analysis), so attack the ~125us non-gather chunk: (1) EPW 8192->4096
// doubles partition parallelism (36KB LDS -> 4 blk/CU); (2) fill2 walks whole
// segments per-lane (avg 10 edges) instead of 64-lane-striding 21-edge
// segments (33% lane util); (3) gather 8/4/1 unroll ladder for deeper MLP.

static constexpr int USERS  = 50000;
static constexpr int NNODES = 100000;
static constexpr int DIM    = 128;
static constexpr int NEDGES = 1600000;
static constexpr long NELEM = (long)NNODES * DIM;     // 12.8M
static constexpr int NBK    = (NNODES + 255) / 256;   // 391 buckets x 256 nodes
static constexpr int EPW    = 4096;                   // edges per partition WG
static constexpr int NWG    = (NEDGES + EPW - 1) / EPW; // 391
static constexpr int SSROW  = NBK + 1;                // 392
static constexpr int INITB  = (int)((NELEM / 16 + 255) / 256); // 3125

__device__ __forceinline__ unsigned short f2bf(float f) {
    unsigned int u = __float_as_uint(f);
    unsigned int r = (u + 0x7FFFu + ((u >> 16) & 1)) >> 16;
    return (unsigned short)r;
}
__device__ __forceinline__ unsigned int pack2(float a, float b) {
    return (unsigned int)f2bf(a) | ((unsigned int)f2bf(b) << 16);
}
__device__ __forceinline__ float bflo(unsigned int p) { return __uint_as_float(p << 16); }
__device__ __forceinline__ float bfhi(unsigned int p) { return __uint_as_float(p & 0xFFFF0000u); }

// ---------- fused: blocks [0,NWG) partition edges; rest convert embeds ----------
__global__ void __launch_bounds__(256) initpart_k(
    const float* __restrict__ uE, const float* __restrict__ iE,
    const int* __restrict__ esrc, const int* __restrict__ edst,
    const float* __restrict__ eval,
    unsigned int* __restrict__ E0, int* __restrict__ ssP,
    int* __restrict__ gcnt, int2* __restrict__ tmp) {
    __shared__ int2 stage[EPW];            // 32 KB
    __shared__ int hist[NBK];
    __shared__ int cursor[NBK];
    __shared__ int sp[256];
    int t = threadIdx.x;

    if (blockIdx.x >= NWG) {
        // ---- init portion: 16 elems/thread ----
        long base = ((long)(blockIdx.x - NWG) * 256 + t) * 16;
        if (base >= NELEM) return;
        const long usplit = (long)USERS * DIM;     // 6.4M, divisible by 16
        const float* s = (base < usplit) ? (uE + base) : (iE + (base - usplit));
        #pragma unroll
        for (int h = 0; h < 2; ++h) {
            float4 f0 = *(const float4*)(s + h * 8);
            float4 f1 = *(const float4*)(s + h * 8 + 4);
            uint4 o;
            o.x = pack2(f0.x, f0.y); o.y = pack2(f0.z, f0.w);
            o.z = pack2(f1.x, f1.y); o.w = pack2(f1.z, f1.w);
            *(uint4*)(E0 + base / 2 + h * 4) = o;
        }
        return;
    }

    // ---- partition portion ----
    int w = blockIdx.x;
    int ebase = w * EPW;
    int n = NEDGES - ebase; if (n > EPW) n = EPW;

    for (int b = t; b < NBK; b += 256) hist[b] = 0;
    __syncthreads();
    #pragma unroll
    for (int k = 0; k < EPW / 256; ++k) {
        int idx = k * 256 + t;
        if (idx < n) atomicAdd(&hist[edst[ebase + idx] >> 8], 1);
    }
    __syncthreads();
    // export bucket totals to global counts
    for (int b = t; b < NBK; b += 256)
        if (hist[b]) atomicAdd(&gcnt[b], hist[b]);
    // exclusive scan hist -> cursor
    int b0 = 2 * t, b1 = 2 * t + 1;
    int v0 = (b0 < NBK) ? hist[b0] : 0;
    int v1 = (b1 < NBK) ? hist[b1] : 0;
    int psum = v0 + v1;
    sp[t] = psum;
    __syncthreads();
    for (int o = 1; o < 256; o <<= 1) {
        int x = (t >= o) ? sp[t - o] : 0;
        __syncthreads();
        sp[t] += x;
        __syncthreads();
    }
    int pref = sp[t] - psum;
    if (b0 < NBK) cursor[b0] = pref;
    if (b1 < NBK) cursor[b1] = pref + v0;
    __syncthreads();
    for (int b = t; b < NBK; b += 256) ssP[w * SSROW + b] = cursor[b];
    if (t == 0) ssP[w * SSROW + NBK] = n;
    __syncthreads();
    #pragma unroll
    for (int k = 0; k < EPW / 256; ++k) {
        int idx = k * 256 + t;
        if (idx < n) {
            int e = ebase + idx;
            int d = edst[e];
            int p = atomicAdd(&cursor[d >> 8], 1);
            stage[p] = make_int2(esrc[e] | ((d & 255) << 17), __float_as_int(eval[e]));
        }
    }
    __syncthreads();
    #pragma unroll
    for (int k = 0; k < EPW / 256; ++k) {
        int idx = k * 256 + t;
        if (idx < n) tmp[ebase + idx] = stage[idx];
    }
}

// per-bucket finalize: lane-per-segment (avg ~10 edges serial per thread,
// ~100% lane utilization), LDS node count+scan -> rs, packed 4B meta.
__global__ void __launch_bounds__(256) fill2_k(
    const int2* __restrict__ tmp, const int* __restrict__ ssP,
    const int* __restrict__ gcnt,
    int* __restrict__ rs, unsigned int* __restrict__ meta) {
    __shared__ int cnt[256];
    __shared__ int cur[256];
    __shared__ int sp2[256];
    __shared__ int sbase;
    int b = blockIdx.x, t = threadIdx.x;
    // bucket base: redundant exclusive scan of gcnt (391)
    int b0 = 2 * t, b1 = 2 * t + 1;
    int g0 = (b0 < NBK) ? gcnt[b0] : 0;
    int g1 = (b1 < NBK) ? gcnt[b1] : 0;
    int ps = g0 + g1;
    sp2[t] = ps;
    __syncthreads();
    for (int o = 1; o < 256; o <<= 1) {
        int x = (t >= o) ? sp2[t - o] : 0;
        __syncthreads();
        sp2[t] += x;
        __syncthreads();
    }
    int pref = sp2[t] - ps;
    if (b0 == b) sbase = pref;
    if (b1 == b) sbase = pref + g0;
    if (b == 0 && t == 0) rs[NNODES] = NEDGES;
    cnt[t] = 0;
    __syncthreads();
    int base = sbase;
    // pass A: count (thread t owns segments w = t, t+256, ...)
    for (int w = t; w < NWG; w += 256) {
        int s = ssP[w * SSROW + b];
        int e = ssP[w * SSROW + b + 1];
        const int2* seg = tmp + (long)w * EPW;
        for (int i = s; i < e; ++i)
            atomicAdd(&cnt[(seg[i].x >> 17) & 255], 1);
    }
    __syncthreads();
    int myc = cnt[t];
    sp2[t] = myc;
    __syncthreads();
    for (int o = 1; o < 256; o <<= 1) {
        int x = (t >= o) ? sp2[t - o] : 0;
        __syncthreads();
        sp2[t] += x;
        __syncthreads();
    }
    int start = base + sp2[t] - myc;
    int node = b * 256 + t;
    if (node < NNODES) rs[node] = start;
    cur[t] = start;
    __syncthreads();
    // pass B: place
    for (int w = t; w < NWG; w += 256) {
        int s = ssP[w * SSROW + b];
        int e = ssP[w * SSROW + b + 1];
        const int2* seg = tmp + (long)w * EPW;
        for (int i = s; i < e; ++i) {
            int2 m = seg[i];
            int slot = atomicAdd(&cur[(m.x >> 17) & 255], 1);
            unsigned int bv = (unsigned int)(f2bf(__int_as_float(m.y)) & 0x7FFF);
            meta[slot] = (unsigned int)(m.x & 0x1FFFF) | (bv << 17);
        }
    }
}

// ---------- gather core: 8/4/1 unroll ladder ----------
__device__ __forceinline__ void gather_row(
    const unsigned int* __restrict__ meta, const unsigned int* __restrict__ cur,
    int beg, int end, int lane, float& outx, float& outy) {
    float accx[8], accy[8];
    #pragma unroll
    for (int k = 0; k < 8; ++k) { accx[k] = 0.f; accy[k] = 0.f; }
    int i = beg;
    for (; i + 8 <= end; i += 8) {
        unsigned int m[8], p[8];
        #pragma unroll
        for (int k = 0; k < 8; ++k) m[k] = __builtin_nontemporal_load(&meta[i + k]);
        #pragma unroll
        for (int k = 0; k < 8; ++k) p[k] = cur[((m[k] & 0x1FFFF) << 6) + lane];
        #pragma unroll
        for (int k = 0; k < 8; ++k) {
            float v = __uint_as_float((m[k] >> 17) << 16);
            accx[k] += bflo(p[k]) * v;
            accy[k] += bfhi(p[k]) * v;
        }
    }
    if (i + 4 <= end) {
        unsigned int m[4], p[4];
        #pragma unroll
        for (int k = 0; k < 4; ++k) m[k] = __builtin_nontemporal_load(&meta[i + k]);
        #pragma unroll
        for (int k = 0; k < 4; ++k) p[k] = cur[((m[k] & 0x1FFFF) << 6) + lane];
        #pragma unroll
        for (int k = 0; k < 4; ++k) {
            float v = __uint_as_float((m[k] >> 17) << 16);
            accx[k] += bflo(p[k]) * v;
            accy[k] += bfhi(p[k]) * v;
        }
        i += 4;
    }
    for (; i < end; ++i) {
        unsigned int m = __builtin_nontemporal_load(&meta[i]);
        unsigned int p = cur[((m & 0x1FFFF) << 6) + lane];
        float v = __uint_as_float((m >> 17) << 16);
        accx[0] += bflo(p) * v;
        accy[0] += bfhi(p) * v;
    }
    outx = ((accx[0] + accx[1]) + (accx[2] + accx[3]))
         + ((accx[4] + accx[5]) + (accx[6] + accx[7]));
    outy = ((accy[0] + accy[1]) + (accy[2] + accy[3]))
         + ((accy[4] + accy[5]) + (accy[6] + accy[7]));
}

// ---------- gather (layers 1,2): 1 wave/row ----------
__global__ void __launch_bounds__(256) gather_k(
    const int* __restrict__ rs, const unsigned int* __restrict__ meta,
    const unsigned int* __restrict__ cur, unsigned int* __restrict__ nxt) {
    int row = blockIdx.x * 4 + (threadIdx.x >> 6);
    if (row >= NNODES) return;
    int lane = threadIdx.x & 63;
    float sx, sy;
    gather_row(meta, cur, rs[row], rs[row + 1], lane, sx, sy);
    nxt[(row << 6) + lane] = pack2(sx, sy);
}

// ---------- layer 3 fused with final: out = E0 + L1 + L2 + sum ----------
__global__ void __launch_bounds__(256) gather_last_k(
    const int* __restrict__ rs, const unsigned int* __restrict__ meta,
    const unsigned int* __restrict__ cur,   // = L2 buffer
    const unsigned int* __restrict__ L1,
    const unsigned int* __restrict__ E0,
    float* __restrict__ out) {
    int row = blockIdx.x * 4 + (threadIdx.x >> 6);
    if (row >= NNODES) return;
    int lane = threadIdx.x & 63;
    float sx, sy;
    gather_row(meta, cur, rs[row], rs[row + 1], lane, sx, sy);
    unsigned int e0 = E0[(row << 6) + lane];
    unsigned int l1 = L1[(row << 6) + lane];
    unsigned int l2 = cur[(row << 6) + lane];
    float2 o;
    o.x = bflo(e0) + bflo(l1) + bflo(l2) + sx;
    o.y = bfhi(e0) + bfhi(l1) + bfhi(l2) + sy;
    *(float2*)(out + (long)row * DIM + lane * 2) = o;
}

// ---------- fallback: R2 atomic path ----------
__global__ void init_f32_k(const float* __restrict__ uE, const float* __restrict__ iE,
                           float* __restrict__ acc, float* __restrict__ cur) {
    long base = ((long)blockIdx.x * blockDim.x + threadIdx.x) * 8;
    if (base >= NELEM) return;
    const long usplit = (long)USERS * DIM;
    const float* s = (base < usplit) ? (uE + base) : (iE + (base - usplit));
    float4 f0 = *(const float4*)(s);
    float4 f1 = *(const float4*)(s + 4);
    *(float4*)(acc + base)     = f0;
    *(float4*)(acc + base + 4) = f1;
    *(float4*)(cur + base)     = f0;
    *(float4*)(cur + base + 4) = f1;
}
__global__ void scatter_k(const int* __restrict__ esrc, const int* __restrict__ edst,
                          const float* __restrict__ eval,
                          const float* __restrict__ cur, float* __restrict__ nxt) {
    long g = (long)blockIdx.x * blockDim.x + threadIdx.x;
    if (g >= (long)NEDGES * 32) return;
    int e  = (int)(g >> 5);
    int d0 = ((int)g & 31) * 4;
    float v = eval[e];
    float4 x = *(const float4*)(cur + (long)esrc[e] * DIM + d0);
    float* o = nxt + (long)edst[e] * DIM + d0;
    unsafeAtomicAdd(o + 0, x.x * v);
    unsafeAtomicAdd(o + 1, x.y * v);
    unsafeAtomicAdd(o + 2, x.z * v);
    unsafeAtomicAdd(o + 3, x.w * v);
}
__global__ void add_k(float* __restrict__ acc, const float* __restrict__ nxt) {
    long g = ((long)blockIdx.x * blockDim.x + threadIdx.x) * 4;
    if (g >= NELEM) return;
    float4 a = *(const float4*)(acc + g);
    float4 n = *(const float4*)(nxt + g);
    a.x += n.x; a.y += n.y; a.z += n.z; a.w += n.w;
    *(float4*)(acc + g) = a;
}

extern "C" void kernel_launch(void* const* d_in, const int* in_sizes, int n_in,
                              void* d_out, int out_size, void* d_ws, size_t ws_size,
                              hipStream_t stream) {
    const float* uE   = (const float*)d_in[0];
    const float* iE   = (const float*)d_in[1];
    const int*   esrc = (const int*)d_in[2];
    const int*   edst = (const int*)d_in[3];
    const float* eval = (const float*)d_in[4];
    float* out = (float*)d_out;

    char* ws = (char*)d_ws;
    const long NU = NELEM / 2;                      // uints per layer buffer
    unsigned int* E0  = (unsigned int*)ws;          // 25.6 MB
    unsigned int* L1  = E0 + NU;                    // 25.6 MB
    unsigned int* L2b = L1 + NU;                    // 25.6 MB
    unsigned int* meta = (unsigned int*)(L2b + NU); // 6.4 MB (packed)
    int*  rs     = (int*)(meta + NEDGES);           // NNODES+1
    int*  gcnt   = rs + NNODES + 1;                 // NBK
    int*  ssP    = gcnt + NBK;                      // NWG*SSROW (0.61 MB)
    size_t need  = (size_t)((char*)(ssP + NWG * SSROW) - ws);
    // tmp aliases L2b: written by part portion, consumed by fill2_k, both
    // complete before gather2 writes L2b.
    int2* tmp = (int2*)L2b;

    if (ws_size >= need) {
        hipMemsetAsync(gcnt, 0, (size_t)NBK * sizeof(int), stream);
        initpart_k<<<NWG + INITB, 256, 0, stream>>>(uE, iE, esrc, edst, eval,
                                                    E0, ssP, gcnt, tmp);
        fill2_k<<<NBK, 256, 0, stream>>>(tmp, ssP, gcnt, rs, meta);

        const int gblocks = (NNODES + 3) / 4;
        gather_k<<<gblocks, 256, 0, stream>>>(rs, meta, E0, L1);
        gather_k<<<gblocks, 256, 0, stream>>>(rs, meta, L1, L2b);
        gather_last_k<<<gblocks, 256, 0, stream>>>(rs, meta, L2b, L1, E0, out);
    } else {
        float* bufA = (float*)ws;
        float* bufB = bufA + NELEM;
        const size_t SZ = (size_t)NELEM * sizeof(float);
        init_f32_k<<<(int)((NELEM / 8 + 255) / 256), 256, 0, stream>>>(uE, iE, out, bufA);
        float* cur = bufA;
        float* nxt = bufB;
        for (int l = 0; l < 3; ++l) {
            hipMemsetAsync(nxt, 0, SZ, stream);
            long nthreads = (long)NEDGES * 32;
            scatter_k<<<(int)((nthreads + 255) / 256), 256, 0, stream>>>(esrc, edst, eval, cur, nxt);
            add_k<<<(int)((NELEM / 4 + 255) / 256), 256, 0, stream>>>(out, nxt);
            float* t = cur; cur = nxt; nxt = t;
        }
    }
}

// Round 11
// 276.599 us; speedup vs baseline: 3.2594x; 1.0697x over previous
//
#include <hip/hip_runtime.h>

// LightGCN: 3-layer propagation, 1.6M edges, D=128.
// R11: (1) uint2 gather -- 32 lanes/row, 2 rows/wave, 4-wide unroll: same
// in-flight bytes as R10's 8-wide uint but half the load/address instructions
// per byte (R10 showed VALUBusy 48% -> partially issue-bound), VGPR<64 keeps
// 8 waves/SIMD. (2) fill2 single-pass: bucket edges staged in 40KB LDS via
// per-thread segment-length scan (no atomics), count/scan/place from LDS --
// removes the second global read of tmp. Build rest = R10 proven.

static constexpr int USERS  = 50000;
static constexpr int NNODES = 100000;
static constexpr int DIM    = 128;
static constexpr int NEDGES = 1600000;
static constexpr long NELEM = (long)NNODES * DIM;     // 12.8M
static constexpr int NBK    = (NNODES + 255) / 256;   // 391 buckets x 256 nodes
static constexpr int EPW    = 4096;                   // edges per partition WG
static constexpr int NWG    = (NEDGES + EPW - 1) / EPW; // 391
static constexpr int SSROW  = NBK + 1;                // 392
static constexpr int INITB  = (int)((NELEM / 16 + 255) / 256); // 3125
static constexpr int SCAP   = 5120;                   // fill2 LDS stage capacity

__device__ __forceinline__ unsigned short f2bf(float f) {
    unsigned int u = __float_as_uint(f);
    unsigned int r = (u + 0x7FFFu + ((u >> 16) & 1)) >> 16;
    return (unsigned short)r;
}
__device__ __forceinline__ unsigned int pack2(float a, float b) {
    return (unsigned int)f2bf(a) | ((unsigned int)f2bf(b) << 16);
}
__device__ __forceinline__ float bflo(unsigned int p) { return __uint_as_float(p << 16); }
__device__ __forceinline__ float bfhi(unsigned int p) { return __uint_as_float(p & 0xFFFF0000u); }

// ---------- fused: blocks [0,NWG) partition edges; rest convert embeds ----------
__global__ void __launch_bounds__(256) initpart_k(
    const float* __restrict__ uE, const float* __restrict__ iE,
    const int* __restrict__ esrc, const int* __restrict__ edst,
    const float* __restrict__ eval,
    unsigned int* __restrict__ E0, int* __restrict__ ssP,
    int* __restrict__ gcnt, int2* __restrict__ tmp) {
    __shared__ int2 stage[EPW];            // 32 KB
    __shared__ int hist[NBK];
    __shared__ int cursor[NBK];
    __shared__ int sp[256];
    int t = threadIdx.x;

    if (blockIdx.x >= NWG) {
        long base = ((long)(blockIdx.x - NWG) * 256 + t) * 16;
        if (base >= NELEM) return;
        const long usplit = (long)USERS * DIM;     // 6.4M, divisible by 16
        const float* s = (base < usplit) ? (uE + base) : (iE + (base - usplit));
        #pragma unroll
        for (int h = 0; h < 2; ++h) {
            float4 f0 = *(const float4*)(s + h * 8);
            float4 f1 = *(const float4*)(s + h * 8 + 4);
            uint4 o;
            o.x = pack2(f0.x, f0.y); o.y = pack2(f0.z, f0.w);
            o.z = pack2(f1.x, f1.y); o.w = pack2(f1.z, f1.w);
            *(uint4*)(E0 + base / 2 + h * 4) = o;
        }
        return;
    }

    int w = blockIdx.x;
    int ebase = w * EPW;
    int n = NEDGES - ebase; if (n > EPW) n = EPW;

    for (int b = t; b < NBK; b += 256) hist[b] = 0;
    __syncthreads();
    #pragma unroll
    for (int k = 0; k < EPW / 256; ++k) {
        int idx = k * 256 + t;
        if (idx < n) atomicAdd(&hist[edst[ebase + idx] >> 8], 1);
    }
    __syncthreads();
    for (int b = t; b < NBK; b += 256)
        if (hist[b]) atomicAdd(&gcnt[b], hist[b]);
    int b0 = 2 * t, b1 = 2 * t + 1;
    int v0 = (b0 < NBK) ? hist[b0] : 0;
    int v1 = (b1 < NBK) ? hist[b1] : 0;
    int psum = v0 + v1;
    sp[t] = psum;
    __syncthreads();
    for (int o = 1; o < 256; o <<= 1) {
        int x = (t >= o) ? sp[t - o] : 0;
        __syncthreads();
        sp[t] += x;
        __syncthreads();
    }
    int pref = sp[t] - psum;
    if (b0 < NBK) cursor[b0] = pref;
    if (b1 < NBK) cursor[b1] = pref + v0;
    __syncthreads();
    for (int b = t; b < NBK; b += 256) ssP[w * SSROW + b] = cursor[b];
    if (t == 0) ssP[w * SSROW + NBK] = n;
    __syncthreads();
    #pragma unroll
    for (int k = 0; k < EPW / 256; ++k) {
        int idx = k * 256 + t;
        if (idx < n) {
            int e = ebase + idx;
            int d = edst[e];
            int p = atomicAdd(&cursor[d >> 8], 1);
            stage[p] = make_int2(esrc[e] | ((d & 255) << 17), __float_as_int(eval[e]));
        }
    }
    __syncthreads();
    #pragma unroll
    for (int k = 0; k < EPW / 256; ++k) {
        int idx = k * 256 + t;
        if (idx < n) tmp[ebase + idx] = stage[idx];
    }
}

// per-bucket finalize, single-pass: LDS-stage bucket edges (no-atomic copy via
// per-thread length scan), count+scan -> rs[], place -> packed 4B meta.
__global__ void __launch_bounds__(256) fill2_k(
    const int2* __restrict__ tmp, const int* __restrict__ ssP,
    const int* __restrict__ gcnt,
    int* __restrict__ rs, unsigned int* __restrict__ meta) {
    __shared__ int2 stage[SCAP];           // 40 KB
    __shared__ int cnt[256];
    __shared__ int cur[256];
    __shared__ int sp2[256];
    __shared__ int sbase;
    int b = blockIdx.x, t = threadIdx.x;

    // bucket base: redundant exclusive scan of gcnt (391)
    int b0 = 2 * t, b1 = 2 * t + 1;
    int g0 = (b0 < NBK) ? gcnt[b0] : 0;
    int g1 = (b1 < NBK) ? gcnt[b1] : 0;
    int ps = g0 + g1;
    sp2[t] = ps;
    __syncthreads();
    for (int o = 1; o < 256; o <<= 1) {
        int x = (t >= o) ? sp2[t - o] : 0;
        __syncthreads();
        sp2[t] += x;
        __syncthreads();
    }
    int pref = sp2[t] - ps;
    if (b0 == b) sbase = pref;
    if (b1 == b) sbase = pref + g0;
    if (b == 0 && t == 0) rs[NNODES] = NEDGES;
    __syncthreads();
    int base = sbase;

    // per-thread segment length sum -> exclusive scan -> stage offsets
    int mylen = 0;
    for (int w = t; w < NWG; w += 256)
        mylen += ssP[w * SSROW + b + 1] - ssP[w * SSROW + b];
    sp2[t] = mylen;
    __syncthreads();
    for (int o = 1; o < 256; o <<= 1) {
        int x = (t >= o) ? sp2[t - o] : 0;
        __syncthreads();
        sp2[t] += x;
        __syncthreads();
    }
    int myoff = sp2[t] - mylen;
    int nb = sp2[255];                      // bucket total
    __syncthreads();

    if (nb <= SCAP) {
        // stage: sequential LDS writes at scanned offsets (no atomics)
        int o = myoff;
        for (int w = t; w < NWG; w += 256) {
            int s = ssP[w * SSROW + b];
            int e = ssP[w * SSROW + b + 1];
            const int2* seg = tmp + (long)w * EPW;
            for (int i = s; i < e; ++i) stage[o++] = seg[i];
        }
        cnt[t] = 0;
        __syncthreads();
        for (int i = t; i < nb; i += 256)
            atomicAdd(&cnt[(stage[i].x >> 17) & 255], 1);
        __syncthreads();
        int myc = cnt[t];
        sp2[t] = myc;
        __syncthreads();
        for (int o2 = 1; o2 < 256; o2 <<= 1) {
            int x = (t >= o2) ? sp2[t - o2] : 0;
            __syncthreads();
            sp2[t] += x;
            __syncthreads();
        }
        int start = base + sp2[t] - myc;
        int node = b * 256 + t;
        if (node < NNODES) rs[node] = start;
        cur[t] = start;
        __syncthreads();
        for (int i = t; i < nb; i += 256) {
            int2 m = stage[i];
            int slot = atomicAdd(&cur[(m.x >> 17) & 255], 1);
            unsigned int bv = (unsigned int)(f2bf(__int_as_float(m.y)) & 0x7FFF);
            meta[slot] = (unsigned int)(m.x & 0x1FFFF) | (bv << 17);
        }
    } else {
        // fallback: two-pass from global (statistically never; kept for safety)
        cnt[t] = 0;
        __syncthreads();
        for (int w = t; w < NWG; w += 256) {
            int s = ssP[w * SSROW + b];
            int e = ssP[w * SSROW + b + 1];
            const int2* seg = tmp + (long)w * EPW;
            for (int i = s; i < e; ++i)
                atomicAdd(&cnt[(seg[i].x >> 17) & 255], 1);
        }
        __syncthreads();
        int myc = cnt[t];
        sp2[t] = myc;
        __syncthreads();
        for (int o2 = 1; o2 < 256; o2 <<= 1) {
            int x = (t >= o2) ? sp2[t - o2] : 0;
            __syncthreads();
            sp2[t] += x;
            __syncthreads();
        }
        int start = base + sp2[t] - myc;
        int node = b * 256 + t;
        if (node < NNODES) rs[node] = start;
        cur[t] = start;
        __syncthreads();
        for (int w = t; w < NWG; w += 256) {
            int s = ssP[w * SSROW + b];
            int e = ssP[w * SSROW + b + 1];
            const int2* seg = tmp + (long)w * EPW;
            for (int i = s; i < e; ++i) {
                int2 m = seg[i];
                int slot = atomicAdd(&cur[(m.x >> 17) & 255], 1);
                unsigned int bv = (unsigned int)(f2bf(__int_as_float(m.y)) & 0x7FFF);
                meta[slot] = (unsigned int)(m.x & 0x1FFFF) | (bv << 17);
            }
        }
    }
}

// ---------- gather core: uint2/lane, 32 lanes/row, 4-wide unroll ----------
__device__ __forceinline__ void gather_row_u2(
    const unsigned int* __restrict__ meta, const uint2* __restrict__ curU2,
    int beg, int end, int sub, float& s0, float& s1, float& s2, float& s3) {
    float a[4][4];
    #pragma unroll
    for (int k = 0; k < 4; ++k)
        #pragma unroll
        for (int j = 0; j < 4; ++j) a[k][j] = 0.f;
    int i = beg;
    for (; i + 4 <= end; i += 4) {
        unsigned int m[4];
        uint2 p[4];
        #pragma unroll
        for (int k = 0; k < 4; ++k) m[k] = __builtin_nontemporal_load(&meta[i + k]);
        #pragma unroll
        for (int k = 0; k < 4; ++k) p[k] = curU2[((m[k] & 0x1FFFF) << 5) + sub];
        #pragma unroll
        for (int k = 0; k < 4; ++k) {
            float v = __uint_as_float((m[k] >> 17) << 16);
            a[k][0] += bflo(p[k].x) * v;
            a[k][1] += bfhi(p[k].x) * v;
            a[k][2] += bflo(p[k].y) * v;
            a[k][3] += bfhi(p[k].y) * v;
        }
    }
    for (; i < end; ++i) {
        unsigned int m = __builtin_nontemporal_load(&meta[i]);
        uint2 p = curU2[((m & 0x1FFFF) << 5) + sub];
        float v = __uint_as_float((m >> 17) << 16);
        a[0][0] += bflo(p.x) * v;
        a[0][1] += bfhi(p.x) * v;
        a[0][2] += bflo(p.y) * v;
        a[0][3] += bfhi(p.y) * v;
    }
    s0 = (a[0][0] + a[1][0]) + (a[2][0] + a[3][0]);
    s1 = (a[0][1] + a[1][1]) + (a[2][1] + a[3][1]);
    s2 = (a[0][2] + a[1][2]) + (a[2][2] + a[3][2]);
    s3 = (a[0][3] + a[1][3]) + (a[2][3] + a[3][3]);
}

// ---------- gather (layers 1,2): 2 rows/wave, 8 rows/block ----------
__global__ void __launch_bounds__(256) gather_k(
    const int* __restrict__ rs, const unsigned int* __restrict__ meta,
    const uint2* __restrict__ cur, uint2* __restrict__ nxt) {
    int lane = threadIdx.x & 63;
    int row = blockIdx.x * 8 + (threadIdx.x >> 6) * 2 + (lane >> 5);
    if (row >= NNODES) return;
    int sub = lane & 31;
    float s0, s1, s2, s3;
    gather_row_u2(meta, cur, rs[row], rs[row + 1], sub, s0, s1, s2, s3);
    nxt[(row << 5) + sub] = make_uint2(pack2(s0, s1), pack2(s2, s3));
}

// ---------- layer 3 fused with final: out = E0 + L1 + L2 + sum ----------
__global__ void __launch_bounds__(256) gather_last_k(
    const int* __restrict__ rs, const unsigned int* __restrict__ meta,
    const uint2* __restrict__ cur,   // = L2 buffer
    const uint2* __restrict__ L1,
    const uint2* __restrict__ E0,
    float* __restrict__ out) {
    int lane = threadIdx.x & 63;
    int row = blockIdx.x * 8 + (threadIdx.x >> 6) * 2 + (lane >> 5);
    if (row >= NNODES) return;
    int sub = lane & 31;
    float s0, s1, s2, s3;
    gather_row_u2(meta, cur, rs[row], rs[row + 1], sub, s0, s1, s2, s3);
    uint2 e0 = E0[(row << 5) + sub];
    uint2 l1 = L1[(row << 5) + sub];
    uint2 l2 = cur[(row << 5) + sub];
    float4 o;
    o.x = bflo(e0.x) + bflo(l1.x) + bflo(l2.x) + s0;
    o.y = bfhi(e0.x) + bfhi(l1.x) + bfhi(l2.x) + s1;
    o.z = bflo(e0.y) + bflo(l1.y) + bflo(l2.y) + s2;
    o.w = bfhi(e0.y) + bfhi(l1.y) + bfhi(l2.y) + s3;
    *(float4*)(out + (long)row * DIM + sub * 4) = o;
}

// ---------- fallback: R2 atomic path ----------
__global__ void init_f32_k(const float* __restrict__ uE, const float* __restrict__ iE,
                           float* __restrict__ acc, float* __restrict__ cur) {
    long base = ((long)blockIdx.x * blockDim.x + threadIdx.x) * 8;
    if (base >= NELEM) return;
    const long usplit = (long)USERS * DIM;
    const float* s = (base < usplit) ? (uE + base) : (iE + (base - usplit));
    float4 f0 = *(const float4*)(s);
    float4 f1 = *(const float4*)(s + 4);
    *(float4*)(acc + base)     = f0;
    *(float4*)(acc + base + 4) = f1;
    *(float4*)(cur + base)     = f0;
    *(float4*)(cur + base + 4) = f1;
}
__global__ void scatter_k(const int* __restrict__ esrc, const int* __restrict__ edst,
                          const float* __restrict__ eval,
                          const float* __restrict__ cur, float* __restrict__ nxt) {
    long g = (long)blockIdx.x * blockDim.x + threadIdx.x;
    if (g >= (long)NEDGES * 32) return;
    int e  = (int)(g >> 5);
    int d0 = ((int)g & 31) * 4;
    float v = eval[e];
    float4 x = *(const float4*)(cur + (long)esrc[e] * DIM + d0);
    float* o = nxt + (long)edst[e] * DIM + d0;
    unsafeAtomicAdd(o + 0, x.x * v);
    unsafeAtomicAdd(o + 1, x.y * v);
    unsafeAtomicAdd(o + 2, x.z * v);
    unsafeAtomicAdd(o + 3, x.w * v);
}
__global__ void add_k(float* __restrict__ acc, const float* __restrict__ nxt) {
    long g = ((long)blockIdx.x * blockDim.x + threadIdx.x) * 4;
    if (g >= NELEM) return;
    float4 a = *(const float4*)(acc + g);
    float4 n = *(const float4*)(nxt + g);
    a.x += n.x; a.y += n.y; a.z += n.z; a.w += n.w;
    *(float4*)(acc + g) = a;
}

extern "C" void kernel_launch(void* const* d_in, const int* in_sizes, int n_in,
                              void* d_out, int out_size, void* d_ws, size_t ws_size,
                              hipStream_t stream) {
    const float* uE   = (const float*)d_in[0];
    const float* iE   = (const float*)d_in[1];
    const int*   esrc = (const int*)d_in[2];
    const int*   edst = (const int*)d_in[3];
    const float* eval = (const float*)d_in[4];
    float* out = (float*)d_out;

    char* ws = (char*)d_ws;
    const long NU = NELEM / 2;                      // uints per layer buffer
    unsigned int* E0  = (unsigned int*)ws;          // 25.6 MB
    unsigned int* L1  = E0 + NU;                    // 25.6 MB
    unsigned int* L2b = L1 + NU;                    // 25.6 MB
    unsigned int* meta = (unsigned int*)(L2b + NU); // 6.4 MB (packed)
    int*  rs     = (int*)(meta + NEDGES);           // NNODES+1
    int*  gcnt   = rs + NNODES + 1;                 // NBK
    int*  ssP    = gcnt + NBK;                      // NWG*SSROW (0.61 MB)
    size_t need  = (size_t)((char*)(ssP + NWG * SSROW) - ws);
    // tmp aliases L2b: written by part portion, consumed by fill2_k, both
    // complete before gather2 writes L2b.
    int2* tmp = (int2*)L2b;

    if (ws_size >= need) {
        hipMemsetAsync(gcnt, 0, (size_t)NBK * sizeof(int), stream);
        initpart_k<<<NWG + INITB, 256, 0, stream>>>(uE, iE, esrc, edst, eval,
                                                    E0, ssP, gcnt, tmp);
        fill2_k<<<NBK, 256, 0, stream>>>(tmp, ssP, gcnt, rs, meta);

        const int gblocks = (NNODES + 7) / 8;
        gather_k<<<gblocks, 256, 0, stream>>>(rs, meta, (const uint2*)E0, (uint2*)L1);
        gather_k<<<gblocks, 256, 0, stream>>>(rs, meta, (const uint2*)L1, (uint2*)L2b);
        gather_last_k<<<gblocks, 256, 0, stream>>>(rs, meta, (const uint2*)L2b,
                                                   (const uint2*)L1, (const uint2*)E0, out);
    } else {
        float* bufA = (float*)ws;
        float* bufB = bufA + NELEM;
        const size_t SZ = (size_t)NELEM * sizeof(float);
        init_f32_k<<<(int)((NELEM / 8 + 255) / 256), 256, 0, stream>>>(uE, iE, out, bufA);
        float* cur = bufA;
        float* nxt = bufB;
        for (int l = 0; l < 3; ++l) {
            hipMemsetAsync(nxt, 0, SZ, stream);
            long nthreads = (long)NEDGES * 32;
            scatter_k<<<(int)((nthreads + 255) / 256), 256, 0, stream>>>(esrc, edst, eval, cur, nxt);
            add_k<<<(int)((NELEM / 4 + 255) / 256), 256, 0, stream>>>(out, nxt);
            float* t = cur; cur = nxt; nxt = t;
        }
    }
}

// Round 12
// 267.082 us; speedup vs baseline: 3.3756x; 1.0356x over previous
//
#include <hip/hip_runtime.h>

// LightGCN: 3-layer propagation, 1.6M edges, D=128.
// R12: uint4 gather -- 16 lanes/row (16B/lane), 4 rows/wave, 4-wide unroll
// with 2 accumulator banks. Halves load/addr instructions per byte vs R11's
// uint2 (VALUBusy 34%) and doubles in-flight miss-lines per wave (16 row
// reads vs 8). VGPR ~48 (<=64, no occupancy cliff). Build = R11 proven
// (LDS-staged partition + single-pass LDS fill2, packed 4B meta).

static constexpr int USERS  = 50000;
static constexpr int NNODES = 100000;
static constexpr int DIM    = 128;
static constexpr int NEDGES = 1600000;
static constexpr long NELEM = (long)NNODES * DIM;     // 12.8M
static constexpr int NBK    = (NNODES + 255) / 256;   // 391 buckets x 256 nodes
static constexpr int EPW    = 4096;                   // edges per partition WG
static constexpr int NWG    = (NEDGES + EPW - 1) / EPW; // 391
static constexpr int SSROW  = NBK + 1;                // 392
static constexpr int INITB  = (int)((NELEM / 16 + 255) / 256); // 3125
static constexpr int SCAP   = 5120;                   // fill2 LDS stage capacity

__device__ __forceinline__ unsigned short f2bf(float f) {
    unsigned int u = __float_as_uint(f);
    unsigned int r = (u + 0x7FFFu + ((u >> 16) & 1)) >> 16;
    return (unsigned short)r;
}
__device__ __forceinline__ unsigned int pack2(float a, float b) {
    return (unsigned int)f2bf(a) | ((unsigned int)f2bf(b) << 16);
}
__device__ __forceinline__ float bflo(unsigned int p) { return __uint_as_float(p << 16); }
__device__ __forceinline__ float bfhi(unsigned int p) { return __uint_as_float(p & 0xFFFF0000u); }

// ---------- fused: blocks [0,NWG) partition edges; rest convert embeds ----------
__global__ void __launch_bounds__(256) initpart_k(
    const float* __restrict__ uE, const float* __restrict__ iE,
    const int* __restrict__ esrc, const int* __restrict__ edst,
    const float* __restrict__ eval,
    unsigned int* __restrict__ E0, int* __restrict__ ssP,
    int* __restrict__ gcnt, int2* __restrict__ tmp) {
    __shared__ int2 stage[EPW];            // 32 KB
    __shared__ int hist[NBK];
    __shared__ int cursor[NBK];
    __shared__ int sp[256];
    int t = threadIdx.x;

    if (blockIdx.x >= NWG) {
        long base = ((long)(blockIdx.x - NWG) * 256 + t) * 16;
        if (base >= NELEM) return;
        const long usplit = (long)USERS * DIM;     // 6.4M, divisible by 16
        const float* s = (base < usplit) ? (uE + base) : (iE + (base - usplit));
        #pragma unroll
        for (int h = 0; h < 2; ++h) {
            float4 f0 = *(const float4*)(s + h * 8);
            float4 f1 = *(const float4*)(s + h * 8 + 4);
            uint4 o;
            o.x = pack2(f0.x, f0.y); o.y = pack2(f0.z, f0.w);
            o.z = pack2(f1.x, f1.y); o.w = pack2(f1.z, f1.w);
            *(uint4*)(E0 + base / 2 + h * 4) = o;
        }
        return;
    }

    int w = blockIdx.x;
    int ebase = w * EPW;
    int n = NEDGES - ebase; if (n > EPW) n = EPW;

    for (int b = t; b < NBK; b += 256) hist[b] = 0;
    __syncthreads();
    #pragma unroll
    for (int k = 0; k < EPW / 256; ++k) {
        int idx = k * 256 + t;
        if (idx < n) atomicAdd(&hist[edst[ebase + idx] >> 8], 1);
    }
    __syncthreads();
    for (int b = t; b < NBK; b += 256)
        if (hist[b]) atomicAdd(&gcnt[b], hist[b]);
    int b0 = 2 * t, b1 = 2 * t + 1;
    int v0 = (b0 < NBK) ? hist[b0] : 0;
    int v1 = (b1 < NBK) ? hist[b1] : 0;
    int psum = v0 + v1;
    sp[t] = psum;
    __syncthreads();
    for (int o = 1; o < 256; o <<= 1) {
        int x = (t >= o) ? sp[t - o] : 0;
        __syncthreads();
        sp[t] += x;
        __syncthreads();
    }
    int pref = sp[t] - psum;
    if (b0 < NBK) cursor[b0] = pref;
    if (b1 < NBK) cursor[b1] = pref + v0;
    __syncthreads();
    for (int b = t; b < NBK; b += 256) ssP[w * SSROW + b] = cursor[b];
    if (t == 0) ssP[w * SSROW + NBK] = n;
    __syncthreads();
    #pragma unroll
    for (int k = 0; k < EPW / 256; ++k) {
        int idx = k * 256 + t;
        if (idx < n) {
            int e = ebase + idx;
            int d = edst[e];
            int p = atomicAdd(&cursor[d >> 8], 1);
            stage[p] = make_int2(esrc[e] | ((d & 255) << 17), __float_as_int(eval[e]));
        }
    }
    __syncthreads();
    #pragma unroll
    for (int k = 0; k < EPW / 256; ++k) {
        int idx = k * 256 + t;
        if (idx < n) tmp[ebase + idx] = stage[idx];
    }
}

// per-bucket finalize, single-pass: LDS-stage bucket edges (no-atomic copy via
// per-thread length scan), count+scan -> rs[], place -> packed 4B meta.
__global__ void __launch_bounds__(256) fill2_k(
    const int2* __restrict__ tmp, const int* __restrict__ ssP,
    const int* __restrict__ gcnt,
    int* __restrict__ rs, unsigned int* __restrict__ meta) {
    __shared__ int2 stage[SCAP];           // 40 KB
    __shared__ int cnt[256];
    __shared__ int cur[256];
    __shared__ int sp2[256];
    __shared__ int sbase;
    int b = blockIdx.x, t = threadIdx.x;

    int b0 = 2 * t, b1 = 2 * t + 1;
    int g0 = (b0 < NBK) ? gcnt[b0] : 0;
    int g1 = (b1 < NBK) ? gcnt[b1] : 0;
    int ps = g0 + g1;
    sp2[t] = ps;
    __syncthreads();
    for (int o = 1; o < 256; o <<= 1) {
        int x = (t >= o) ? sp2[t - o] : 0;
        __syncthreads();
        sp2[t] += x;
        __syncthreads();
    }
    int pref = sp2[t] - ps;
    if (b0 == b) sbase = pref;
    if (b1 == b) sbase = pref + g0;
    if (b == 0 && t == 0) rs[NNODES] = NEDGES;
    __syncthreads();
    int base = sbase;

    int mylen = 0;
    for (int w = t; w < NWG; w += 256)
        mylen += ssP[w * SSROW + b + 1] - ssP[w * SSROW + b];
    sp2[t] = mylen;
    __syncthreads();
    for (int o = 1; o < 256; o <<= 1) {
        int x = (t >= o) ? sp2[t - o] : 0;
        __syncthreads();
        sp2[t] += x;
        __syncthreads();
    }
    int myoff = sp2[t] - mylen;
    int nb = sp2[255];
    __syncthreads();

    if (nb <= SCAP) {
        int o = myoff;
        for (int w = t; w < NWG; w += 256) {
            int s = ssP[w * SSROW + b];
            int e = ssP[w * SSROW + b + 1];
            const int2* seg = tmp + (long)w * EPW;
            for (int i = s; i < e; ++i) stage[o++] = seg[i];
        }
        cnt[t] = 0;
        __syncthreads();
        for (int i = t; i < nb; i += 256)
            atomicAdd(&cnt[(stage[i].x >> 17) & 255], 1);
        __syncthreads();
        int myc = cnt[t];
        sp2[t] = myc;
        __syncthreads();
        for (int o2 = 1; o2 < 256; o2 <<= 1) {
            int x = (t >= o2) ? sp2[t - o2] : 0;
            __syncthreads();
            sp2[t] += x;
            __syncthreads();
        }
        int start = base + sp2[t] - myc;
        int node = b * 256 + t;
        if (node < NNODES) rs[node] = start;
        cur[t] = start;
        __syncthreads();
        for (int i = t; i < nb; i += 256) {
            int2 m = stage[i];
            int slot = atomicAdd(&cur[(m.x >> 17) & 255], 1);
            unsigned int bv = (unsigned int)(f2bf(__int_as_float(m.y)) & 0x7FFF);
            meta[slot] = (unsigned int)(m.x & 0x1FFFF) | (bv << 17);
        }
    } else {
        cnt[t] = 0;
        __syncthreads();
        for (int w = t; w < NWG; w += 256) {
            int s = ssP[w * SSROW + b];
            int e = ssP[w * SSROW + b + 1];
            const int2* seg = tmp + (long)w * EPW;
            for (int i = s; i < e; ++i)
                atomicAdd(&cnt[(seg[i].x >> 17) & 255], 1);
        }
        __syncthreads();
        int myc = cnt[t];
        sp2[t] = myc;
        __syncthreads();
        for (int o2 = 1; o2 < 256; o2 <<= 1) {
            int x = (t >= o2) ? sp2[t - o2] : 0;
            __syncthreads();
            sp2[t] += x;
            __syncthreads();
        }
        int start = base + sp2[t] - myc;
        int node = b * 256 + t;
        if (node < NNODES) rs[node] = start;
        cur[t] = start;
        __syncthreads();
        for (int w = t; w < NWG; w += 256) {
            int s = ssP[w * SSROW + b];
            int e = ssP[w * SSROW + b + 1];
            const int2* seg = tmp + (long)w * EPW;
            for (int i = s; i < e; ++i) {
                int2 m = seg[i];
                int slot = atomicAdd(&cur[(m.x >> 17) & 255], 1);
                unsigned int bv = (unsigned int)(f2bf(__int_as_float(m.y)) & 0x7FFF);
                meta[slot] = (unsigned int)(m.x & 0x1FFFF) | (bv << 17);
            }
        }
    }
}

// ---------- gather core: uint4/lane, 16 lanes/row, 4-wide unroll, 2 banks ----------
__device__ __forceinline__ void gather_row_u4(
    const unsigned int* __restrict__ meta, const uint4* __restrict__ curU4,
    int beg, int end, int sub, float* __restrict__ s) {
    float a0[8], a1[8];
    #pragma unroll
    for (int j = 0; j < 8; ++j) { a0[j] = 0.f; a1[j] = 0.f; }
    int i = beg;
    for (; i + 4 <= end; i += 4) {
        unsigned int m0 = __builtin_nontemporal_load(&meta[i]);
        unsigned int m1 = __builtin_nontemporal_load(&meta[i + 1]);
        unsigned int m2 = __builtin_nontemporal_load(&meta[i + 2]);
        unsigned int m3 = __builtin_nontemporal_load(&meta[i + 3]);
        uint4 p0 = curU4[((m0 & 0x1FFFF) << 4) + sub];
        uint4 p1 = curU4[((m1 & 0x1FFFF) << 4) + sub];
        uint4 p2 = curU4[((m2 & 0x1FFFF) << 4) + sub];
        uint4 p3 = curU4[((m3 & 0x1FFFF) << 4) + sub];
        float v0 = __uint_as_float((m0 >> 17) << 16);
        float v1 = __uint_as_float((m1 >> 17) << 16);
        float v2 = __uint_as_float((m2 >> 17) << 16);
        float v3 = __uint_as_float((m3 >> 17) << 16);
        a0[0] += bflo(p0.x) * v0; a0[1] += bfhi(p0.x) * v0;
        a0[2] += bflo(p0.y) * v0; a0[3] += bfhi(p0.y) * v0;
        a0[4] += bflo(p0.z) * v0; a0[5] += bfhi(p0.z) * v0;
        a0[6] += bflo(p0.w) * v0; a0[7] += bfhi(p0.w) * v0;
        a1[0] += bflo(p1.x) * v1; a1[1] += bfhi(p1.x) * v1;
        a1[2] += bflo(p1.y) * v1; a1[3] += bfhi(p1.y) * v1;
        a1[4] += bflo(p1.z) * v1; a1[5] += bfhi(p1.z) * v1;
        a1[6] += bflo(p1.w) * v1; a1[7] += bfhi(p1.w) * v1;
        a0[0] += bflo(p2.x) * v2; a0[1] += bfhi(p2.x) * v2;
        a0[2] += bflo(p2.y) * v2; a0[3] += bfhi(p2.y) * v2;
        a0[4] += bflo(p2.z) * v2; a0[5] += bfhi(p2.z) * v2;
        a0[6] += bflo(p2.w) * v2; a0[7] += bfhi(p2.w) * v2;
        a1[0] += bflo(p3.x) * v3; a1[1] += bfhi(p3.x) * v3;
        a1[2] += bflo(p3.y) * v3; a1[3] += bfhi(p3.y) * v3;
        a1[4] += bflo(p3.z) * v3; a1[5] += bfhi(p3.z) * v3;
        a1[6] += bflo(p3.w) * v3; a1[7] += bfhi(p3.w) * v3;
    }
    for (; i < end; ++i) {
        unsigned int m = __builtin_nontemporal_load(&meta[i]);
        uint4 p = curU4[((m & 0x1FFFF) << 4) + sub];
        float v = __uint_as_float((m >> 17) << 16);
        a0[0] += bflo(p.x) * v; a0[1] += bfhi(p.x) * v;
        a0[2] += bflo(p.y) * v; a0[3] += bfhi(p.y) * v;
        a0[4] += bflo(p.z) * v; a0[5] += bfhi(p.z) * v;
        a0[6] += bflo(p.w) * v; a0[7] += bfhi(p.w) * v;
    }
    #pragma unroll
    for (int j = 0; j < 8; ++j) s[j] = a0[j] + a1[j];
}

// ---------- gather (layers 1,2): 4 rows/wave, 16 rows/block ----------
__global__ void __launch_bounds__(256) gather_k(
    const int* __restrict__ rs, const unsigned int* __restrict__ meta,
    const uint4* __restrict__ cur, uint4* __restrict__ nxt) {
    int lane = threadIdx.x & 63;
    int row = blockIdx.x * 16 + (threadIdx.x >> 6) * 4 + (lane >> 4);
    if (row >= NNODES) return;
    int sub = lane & 15;
    float s[8];
    gather_row_u4(meta, cur, rs[row], rs[row + 1], sub, s);
    nxt[(row << 4) + sub] = make_uint4(pack2(s[0], s[1]), pack2(s[2], s[3]),
                                       pack2(s[4], s[5]), pack2(s[6], s[7]));
}

// ---------- layer 3 fused with final: out = E0 + L1 + L2 + sum ----------
__global__ void __launch_bounds__(256) gather_last_k(
    const int* __restrict__ rs, const unsigned int* __restrict__ meta,
    const uint4* __restrict__ cur,   // = L2 buffer
    const uint4* __restrict__ L1,
    const uint4* __restrict__ E0,
    float* __restrict__ out) {
    int lane = threadIdx.x & 63;
    int row = blockIdx.x * 16 + (threadIdx.x >> 6) * 4 + (lane >> 4);
    if (row >= NNODES) return;
    int sub = lane & 15;
    float s[8];
    gather_row_u4(meta, cur, rs[row], rs[row + 1], sub, s);
    uint4 e0 = E0[(row << 4) + sub];
    uint4 l1 = L1[(row << 4) + sub];
    uint4 l2 = cur[(row << 4) + sub];
    float4 o0, o1;
    o0.x = bflo(e0.x) + bflo(l1.x) + bflo(l2.x) + s[0];
    o0.y = bfhi(e0.x) + bfhi(l1.x) + bfhi(l2.x) + s[1];
    o0.z = bflo(e0.y) + bflo(l1.y) + bflo(l2.y) + s[2];
    o0.w = bfhi(e0.y) + bfhi(l1.y) + bfhi(l2.y) + s[3];
    o1.x = bflo(e0.z) + bflo(l1.z) + bflo(l2.z) + s[4];
    o1.y = bfhi(e0.z) + bfhi(l1.z) + bfhi(l2.z) + s[5];
    o1.z = bflo(e0.w) + bflo(l1.w) + bflo(l2.w) + s[6];
    o1.w = bfhi(e0.w) + bfhi(l1.w) + bfhi(l2.w) + s[7];
    float* op = out + (long)row * DIM + sub * 8;
    *(float4*)(op)     = o0;
    *(float4*)(op + 4) = o1;
}

// ---------- fallback: R2 atomic path ----------
__global__ void init_f32_k(const float* __restrict__ uE, const float* __restrict__ iE,
                           float* __restrict__ acc, float* __restrict__ cur) {
    long base = ((long)blockIdx.x * blockDim.x + threadIdx.x) * 8;
    if (base >= NELEM) return;
    const long usplit = (long)USERS * DIM;
    const float* s = (base < usplit) ? (uE + base) : (iE + (base - usplit));
    float4 f0 = *(const float4*)(s);
    float4 f1 = *(const float4*)(s + 4);
    *(float4*)(acc + base)     = f0;
    *(float4*)(acc + base + 4) = f1;
    *(float4*)(cur + base)     = f0;
    *(float4*)(cur + base + 4) = f1;
}
__global__ void scatter_k(const int* __restrict__ esrc, const int* __restrict__ edst,
                          const float* __restrict__ eval,
                          const float* __restrict__ cur, float* __restrict__ nxt) {
    long g = (long)blockIdx.x * blockDim.x + threadIdx.x;
    if (g >= (long)NEDGES * 32) return;
    int e  = (int)(g >> 5);
    int d0 = ((int)g & 31) * 4;
    float v = eval[e];
    float4 x = *(const float4*)(cur + (long)esrc[e] * DIM + d0);
    float* o = nxt + (long)edst[e] * DIM + d0;
    unsafeAtomicAdd(o + 0, x.x * v);
    unsafeAtomicAdd(o + 1, x.y * v);
    unsafeAtomicAdd(o + 2, x.z * v);
    unsafeAtomicAdd(o + 3, x.w * v);
}
__global__ void add_k(float* __restrict__ acc, const float* __restrict__ nxt) {
    long g = ((long)blockIdx.x * blockDim.x + threadIdx.x) * 4;
    if (g >= NELEM) return;
    float4 a = *(const float4*)(acc + g);
    float4 n = *(const float4*)(nxt + g);
    a.x += n.x; a.y += n.y; a.z += n.z; a.w += n.w;
    *(float4*)(acc + g) = a;
}

extern "C" void kernel_launch(void* const* d_in, const int* in_sizes, int n_in,
                              void* d_out, int out_size, void* d_ws, size_t ws_size,
                              hipStream_t stream) {
    const float* uE   = (const float*)d_in[0];
    const float* iE   = (const float*)d_in[1];
    const int*   esrc = (const int*)d_in[2];
    const int*   edst = (const int*)d_in[3];
    const float* eval = (const float*)d_in[4];
    float* out = (float*)d_out;

    char* ws = (char*)d_ws;
    const long NU = NELEM / 2;                      // uints per layer buffer
    unsigned int* E0  = (unsigned int*)ws;          // 25.6 MB
    unsigned int* L1  = E0 + NU;                    // 25.6 MB
    unsigned int* L2b = L1 + NU;                    // 25.6 MB
    unsigned int* meta = (unsigned int*)(L2b + NU); // 6.4 MB (packed)
    int*  rs     = (int*)(meta + NEDGES);           // NNODES+1
    int*  gcnt   = rs + NNODES + 1;                 // NBK
    int*  ssP    = gcnt + NBK;                      // NWG*SSROW (0.61 MB)
    size_t need  = (size_t)((char*)(ssP + NWG * SSROW) - ws);
    int2* tmp = (int2*)L2b;

    if (ws_size >= need) {
        hipMemsetAsync(gcnt, 0, (size_t)NBK * sizeof(int), stream);
        initpart_k<<<NWG + INITB, 256, 0, stream>>>(uE, iE, esrc, edst, eval,
                                                    E0, ssP, gcnt, tmp);
        fill2_k<<<NBK, 256, 0, stream>>>(tmp, ssP, gcnt, rs, meta);

        const int gblocks = (NNODES + 15) / 16;
        gather_k<<<gblocks, 256, 0, stream>>>(rs, meta, (const uint4*)E0, (uint4*)L1);
        gather_k<<<gblocks, 256, 0, stream>>>(rs, meta, (const uint4*)L1, (uint4*)L2b);
        gather_last_k<<<gblocks, 256, 0, stream>>>(rs, meta, (const uint4*)L2b,
                                                   (const uint4*)L1, (const uint4*)E0, out);
    } else {
        float* bufA = (float*)ws;
        float* bufB = bufA + NELEM;
        const size_t SZ = (size_t)NELEM * sizeof(float);
        init_f32_k<<<(int)((NELEM / 8 + 255) / 256), 256, 0, stream>>>(uE, iE, out, bufA);
        float* cur = bufA;
        float* nxt = bufB;
        for (int l = 0; l < 3; ++l) {
            hipMemsetAsync(nxt, 0, SZ, stream);
            long nthreads = (long)NEDGES * 32;
            scatter_k<<<(int)((nthreads + 255) / 256), 256, 0, stream>>>(esrc, edst, eval, cur, nxt);
            add_k<<<(int)((NELEM / 4 + 255) / 256), 256, 0, stream>>>(out, nxt);
            float* t = cur; cur = nxt; nxt = t;
        }
    }
}